// Round 1
// baseline (1008.006 us; speedup 1.0000x reference)
//
#include <hip/hip_runtime.h>
#include <math.h>

#define BATCH 16
#define SEQLEN 4096
#define D_MODEL 96
#define D_STATE 6
#define D_CONV 9
#define D_INNER 192
#define DT_RANK 6
#define NPOS (BATCH * SEQLEN)

#define NC 32            // chunks per sequence
#define CT (SEQLEN / NC) // 128 steps per chunk

// workspace layout (in floats)
#define OFF_XS    0L
#define OFF_Z     (OFF_XS    + (long)NPOS * D_INNER)
#define OFF_XC    (OFF_Z     + (long)NPOS * D_INNER)
#define OFF_DELTA (OFF_XC    + (long)NPOS * D_INNER)
#define OFF_BM    (OFF_DELTA + (long)NPOS * D_INNER)
#define OFF_CM    (OFF_BM    + (long)NPOS * D_STATE)
#define OFF_AC    (OFF_CM    + (long)NPOS * D_STATE)
#define OFF_BC    (OFF_AC    + (long)BATCH * D_INNER * NC * D_STATE)
#define OFF_HIN   (OFF_BC    + (long)BATCH * D_INNER * NC * D_STATE)
#define OFF_YSUM  (OFF_HIN   + (long)BATCH * D_INNER * NC * D_STATE)
#define OFF_XBAR  (OFF_YSUM  + (long)BATCH * D_INNER * NC)

__device__ __forceinline__ float siluf(float v) {
    return v / (1.0f + expf(-v));
}
__device__ __forceinline__ float softplusf(float v) {
    return (v > 20.0f) ? v : log1pf(expf(v));
}
__device__ __forceinline__ float eluf(float v) {
    return (v > 0.0f) ? v : expm1f(v);
}

// ---------------------------------------------------------------------------
// K1: RMSNorm + in_proj (h @ W^T -> xs, z), plus xbar (sum of raw x over L)
// block: 256 threads, 64 positions per block
// ---------------------------------------------------------------------------
#define TP1 64
__global__ __launch_bounds__(256) void k1_rmsnorm_inproj(
    const float* __restrict__ x, const float* __restrict__ W,
    const float* __restrict__ norm_w,
    float* __restrict__ xs, float* __restrict__ z, float* __restrict__ xbar)
{
    __shared__ float hT[96 * 73]; // hT[d*73 + p]
    __shared__ float scale[TP1];
    const int tid = threadIdx.x;
    const long p0 = (long)blockIdx.x * TP1;
    const int b = (int)(p0 / SEQLEN);

    // load x tile transposed into LDS
    for (int i = tid; i < TP1 * 96; i += 256) {
        int p = i / 96, d = i % 96;
        hT[d * 73 + p] = x[(p0 + p) * 96 + d];
    }
    __syncthreads();

    if (tid < TP1) {
        float ss = 0.0f;
        for (int d = 0; d < 96; d++) { float v = hT[d * 73 + tid]; ss += v * v; }
        scale[tid] = 1.0f / sqrtf(ss / 96.0f + 1e-5f);
    } else if (tid < TP1 + 96) {
        int d = tid - TP1;
        float s = 0.0f;
        for (int p = 0; p < TP1; p++) s += hT[d * 73 + p];
        atomicAdd(&xbar[b * 96 + d], s);
    }
    __syncthreads();

    // normalize in place
    for (int i = tid; i < TP1 * 96; i += 256) {
        int d = i >> 6, p = i & 63;
        hT[d * 73 + p] *= scale[p] * norm_w[d];
    }
    __syncthreads();

    // each thread: 12 outputs x 8 positions
    const int jg = tid & 31, pg = tid >> 5;
    const int j0 = jg * 12, pbase = pg * 8;
    float acc[12][8];
#pragma unroll
    for (int jj = 0; jj < 12; jj++)
#pragma unroll
        for (int p = 0; p < 8; p++) acc[jj][p] = 0.0f;

    for (int d = 0; d < 96; d++) {
        float hv[8];
#pragma unroll
        for (int p = 0; p < 8; p++) hv[p] = hT[d * 73 + pbase + p];
#pragma unroll
        for (int jj = 0; jj < 12; jj++) {
            float wv = W[(j0 + jj) * 96 + d];
#pragma unroll
            for (int p = 0; p < 8; p++) acc[jj][p] += wv * hv[p];
        }
    }

    // j0 is a multiple of 12; j<192 iff jg<16 (192=16*12) -> branch is uniform
    float* dst = (j0 < 192) ? xs : z;
    const int jc0 = (j0 < 192) ? j0 : j0 - 192;
#pragma unroll
    for (int jj = 0; jj < 12; jj++) {
#pragma unroll
        for (int p = 0; p < 8; p++) {
            long pos = p0 + pbase + p;
            dst[pos * D_INNER + jc0 + jj] = acc[jj][p];
        }
    }
}

// ---------------------------------------------------------------------------
// K2: causal depthwise conv(9) + silu -> xc;  dbc = xc @ x_proj_w^T;
//     delta = softplus(delta_r @ dt_proj_w^T + dt_b);  store Bm, Cm
// block: 192 threads (one per channel e), 32 positions per block
// ---------------------------------------------------------------------------
#define TP2 32
__global__ __launch_bounds__(192) void k2_conv_proj(
    const float* __restrict__ xs,
    const float* __restrict__ conv_w, const float* __restrict__ conv_b,
    const float* __restrict__ x_proj_w,
    const float* __restrict__ dt_w, const float* __restrict__ dt_b,
    float* __restrict__ xc_out, float* __restrict__ delta_out,
    float* __restrict__ Bm_out, float* __restrict__ Cm_out)
{
    __shared__ float sxc[TP2][D_INNER];
    __shared__ float sdbc[TP2][DT_RANK + 2 * D_STATE];
    const int e = threadIdx.x;
    const long p0 = (long)blockIdx.x * TP2;
    const int b = (int)(p0 / SEQLEN);
    const int l0 = (int)(p0 % SEQLEN);
    const long brow = (long)b * SEQLEN;

    float cw[D_CONV];
#pragma unroll
    for (int k = 0; k < D_CONV; k++) cw[k] = conv_w[e * D_CONV + k];
    const float cb = conv_b[e];

    // rolling window over the causal conv
    float win[D_CONV];
#pragma unroll
    for (int k = 0; k < 8; k++) {
        int ll = l0 - 8 + k;
        win[k] = (ll >= 0) ? xs[(brow + ll) * D_INNER + e] : 0.0f;
    }
    for (int r = 0; r < TP2; r++) {
        win[8] = xs[(brow + l0 + r) * D_INNER + e];
        float s = cb;
#pragma unroll
        for (int k = 0; k < D_CONV; k++) s += win[k] * cw[k];
        float xcv = siluf(s);
        sxc[r][e] = xcv;
        xc_out[(brow + l0 + r) * D_INNER + e] = xcv;
#pragma unroll
        for (int k = 0; k < 8; k++) win[k] = win[k + 1];
    }
    __syncthreads();

    // dbc: 32 positions x 18 outputs, each a 192-dot
    for (int t = e; t < TP2 * 18; t += 192) {
        int p = t / 18, f = t % 18;
        const float* wrow = &x_proj_w[f * D_INNER];
        float s = 0.0f;
        for (int kk = 0; kk < D_INNER; kk++) s += sxc[p][kk] * wrow[kk];
        sdbc[p][f] = s;
        long pos = brow + l0 + p;
        if (f >= 6 && f < 12)      Bm_out[pos * D_STATE + (f - 6)] = s;
        else if (f >= 12)          Cm_out[pos * D_STATE + (f - 12)] = s;
    }
    __syncthreads();

    // delta[e] = softplus(delta_r . dt_w[e,:] + dt_b[e])
    float dtw[DT_RANK];
#pragma unroll
    for (int q = 0; q < DT_RANK; q++) dtw[q] = dt_w[e * DT_RANK + q];
    const float dtb = dt_b[e];
    for (int r = 0; r < TP2; r++) {
        float s = dtb;
#pragma unroll
        for (int q = 0; q < DT_RANK; q++) s += sdbc[r][q] * dtw[q];
        delta_out[(brow + l0 + r) * D_INNER + e] = softplusf(s);
    }
}

// ---------------------------------------------------------------------------
// K3: scan pass A — per (b, e, chunk): cumulative product P and zero-init
// state S over CT steps. block: 192 threads (e), grid: B*NC
// ---------------------------------------------------------------------------
__global__ __launch_bounds__(192) void k3_scanA(
    const float* __restrict__ delta, const float* __restrict__ xc,
    const float* __restrict__ Bm, const float* __restrict__ A_log,
    float* __restrict__ Ac, float* __restrict__ Bc)
{
    const int e = threadIdx.x;
    const int c = blockIdx.x & (NC - 1);
    const int b = blockIdx.x >> 5;
    const long base = (long)b * SEQLEN + (long)c * CT;

    float a[D_STATE];
#pragma unroll
    for (int n = 0; n < D_STATE; n++) a[n] = -expf(A_log[e * D_STATE + n]);

    float P[D_STATE], S[D_STATE];
#pragma unroll
    for (int n = 0; n < D_STATE; n++) { P[n] = 1.0f; S[n] = 0.0f; }

    for (int t = 0; t < CT; t++) {
        long pos = base + t;
        float dl = delta[pos * D_INNER + e];
        float xv = xc[pos * D_INNER + e];
        float dx = dl * xv;
        float bm[D_STATE];
#pragma unroll
        for (int n = 0; n < D_STATE; n++) bm[n] = Bm[pos * D_STATE + n];
#pragma unroll
        for (int n = 0; n < D_STATE; n++) {
            float dA = expf(dl * a[n]);
            S[n] = dA * S[n] + dx * bm[n];
            P[n] *= dA;
        }
    }
    long o = (((long)b * D_INNER + e) * NC + c) * D_STATE;
#pragma unroll
    for (int n = 0; n < D_STATE; n++) { Ac[o + n] = P[n]; Bc[o + n] = S[n]; }
}

// ---------------------------------------------------------------------------
// K4: sequential chunk combine — per (b,e): Hin[c+1] = Ac[c]*Hin[c] + Bc[c]
// ---------------------------------------------------------------------------
__global__ __launch_bounds__(256) void k4_combine(
    const float* __restrict__ Ac, const float* __restrict__ Bc,
    float* __restrict__ Hin)
{
    int idx = blockIdx.x * 256 + threadIdx.x; // (b*192 + e)
    if (idx >= BATCH * D_INNER) return;
    float H[D_STATE];
#pragma unroll
    for (int n = 0; n < D_STATE; n++) H[n] = 0.0f;
    long base = (long)idx * NC * D_STATE;
    for (int c = 0; c < NC; c++) {
        long o = base + (long)c * D_STATE;
#pragma unroll
        for (int n = 0; n < D_STATE; n++) {
            Hin[o + n] = H[n];
            H[n] = Ac[o + n] * H[n] + Bc[o + n];
        }
    }
}

// ---------------------------------------------------------------------------
// K5: scan pass B — replay chunk with correct carry-in; emit per-chunk
// y-sums:  y = (h . Cm + D*xc) * silu(z), accumulated over the chunk
// ---------------------------------------------------------------------------
__global__ __launch_bounds__(192) void k5_scanB(
    const float* __restrict__ delta, const float* __restrict__ xc,
    const float* __restrict__ Bm, const float* __restrict__ Cm,
    const float* __restrict__ z, const float* __restrict__ A_log,
    const float* __restrict__ D_param, const float* __restrict__ Hin,
    float* __restrict__ ysum_part)
{
    const int e = threadIdx.x;
    const int c = blockIdx.x & (NC - 1);
    const int b = blockIdx.x >> 5;
    const long base = (long)b * SEQLEN + (long)c * CT;

    float a[D_STATE];
#pragma unroll
    for (int n = 0; n < D_STATE; n++) a[n] = -expf(A_log[e * D_STATE + n]);
    const float Dv = D_param[e];

    long ho = (((long)b * D_INNER + e) * NC + c) * D_STATE;
    float S[D_STATE];
#pragma unroll
    for (int n = 0; n < D_STATE; n++) S[n] = Hin[ho + n];

    float ysum = 0.0f;
    for (int t = 0; t < CT; t++) {
        long pos = base + t;
        float dl = delta[pos * D_INNER + e];
        float xv = xc[pos * D_INNER + e];
        float zv = z[pos * D_INNER + e];
        float dx = dl * xv;
        float y = 0.0f;
#pragma unroll
        for (int n = 0; n < D_STATE; n++) {
            float dA = expf(dl * a[n]);
            S[n] = dA * S[n] + dx * Bm[pos * D_STATE + n];
            y += S[n] * Cm[pos * D_STATE + n];
        }
        y += Dv * xv;
        y *= siluf(zv);
        ysum += y;
    }
    ysum_part[((long)b * D_INNER + e) * NC + c] = ysum;
}

// ---------------------------------------------------------------------------
// K6: output head — one block per batch element.
// e[b,d] = (xbar + ybar @ Wout^T)/L; feat = elu(tanh(e@Wfc^T+b));
// mu = feat@mu_w^T+mu_b; sigma = elu(feat@sig_w^T+sig_b)+1+1e-14
// ---------------------------------------------------------------------------
__global__ __launch_bounds__(256) void k6_head(
    const float* __restrict__ ysum_part, const float* __restrict__ xbar,
    const float* __restrict__ Wout,
    const float* __restrict__ fc_w, const float* __restrict__ fc_b,
    const float* __restrict__ mu_w, const float* __restrict__ mu_b,
    const float* __restrict__ sg_w, const float* __restrict__ sg_b,
    float* __restrict__ out)
{
    __shared__ float ybar[D_INNER];
    __shared__ float evec[D_MODEL];
    __shared__ float feat_s[64];
    const int b = blockIdx.x;
    const int tid = threadIdx.x;

    if (tid < D_INNER) {
        float s = 0.0f;
        long o = ((long)b * D_INNER + tid) * NC;
        for (int c = 0; c < NC; c++) s += ysum_part[o + c];
        ybar[tid] = s;
    }
    __syncthreads();

    if (tid < D_MODEL) {
        float s = xbar[b * D_MODEL + tid];
        const float* wrow = &Wout[tid * D_INNER];
        for (int e2 = 0; e2 < D_INNER; e2++) s += ybar[e2] * wrow[e2];
        evec[tid] = s / (float)SEQLEN;
    }
    __syncthreads();

    if (tid < 64) {
        float s = fc_b[tid];
        const float* wrow = &fc_w[tid * D_MODEL];
        for (int d = 0; d < D_MODEL; d++) s += evec[d] * wrow[d];
        float f = eluf(tanhf(s));
        feat_s[tid] = f;
        out[b * 64 + tid] = f; // feat
    }
    __syncthreads();

    if (tid < 64) {
        float smu = mu_b[tid], ssg = sg_b[tid];
        const float* mrow = &mu_w[tid * 64];
        const float* srow = &sg_w[tid * 64];
        for (int i = 0; i < 64; i++) {
            smu += feat_s[i] * mrow[i];
            ssg += feat_s[i] * srow[i];
        }
        out[1024 + b * 64 + tid] = smu;                        // mu
        out[2048 + b * 64 + tid] = eluf(ssg) + 1.0f + 1e-14f;  // sigma
    }
}

extern "C" void kernel_launch(void* const* d_in, const int* in_sizes, int n_in,
                              void* d_out, int out_size, void* d_ws, size_t ws_size,
                              hipStream_t stream) {
    const float* x         = (const float*)d_in[0];
    const float* in_proj_w = (const float*)d_in[1];
    const float* conv_w    = (const float*)d_in[2];
    const float* conv_b    = (const float*)d_in[3];
    const float* x_proj_w  = (const float*)d_in[4];
    const float* dt_proj_w = (const float*)d_in[5];
    const float* dt_proj_b = (const float*)d_in[6];
    const float* A_log     = (const float*)d_in[7];
    const float* D_param   = (const float*)d_in[8];
    const float* out_proj_w= (const float*)d_in[9];
    const float* norm_w    = (const float*)d_in[10];
    const float* out_fc_w  = (const float*)d_in[11];
    const float* out_fc_b  = (const float*)d_in[12];
    const float* mu_w      = (const float*)d_in[13];
    const float* mu_b      = (const float*)d_in[14];
    const float* sigma_w   = (const float*)d_in[15];
    const float* sigma_b   = (const float*)d_in[16];
    float* ws = (float*)d_ws;
    float* out = (float*)d_out;

    // zero xbar accumulator (atomicAdd target)
    hipMemsetAsync(ws + OFF_XBAR, 0, BATCH * D_MODEL * sizeof(float), stream);

    k1_rmsnorm_inproj<<<NPOS / TP1, 256, 0, stream>>>(
        x, in_proj_w, norm_w, ws + OFF_XS, ws + OFF_Z, ws + OFF_XBAR);

    k2_conv_proj<<<NPOS / TP2, 192, 0, stream>>>(
        ws + OFF_XS, conv_w, conv_b, x_proj_w, dt_proj_w, dt_proj_b,
        ws + OFF_XC, ws + OFF_DELTA, ws + OFF_BM, ws + OFF_CM);

    k3_scanA<<<BATCH * NC, 192, 0, stream>>>(
        ws + OFF_DELTA, ws + OFF_XC, ws + OFF_BM, A_log,
        ws + OFF_AC, ws + OFF_BC);

    k4_combine<<<(BATCH * D_INNER + 255) / 256, 256, 0, stream>>>(
        ws + OFF_AC, ws + OFF_BC, ws + OFF_HIN);

    k5_scanB<<<BATCH * NC, 192, 0, stream>>>(
        ws + OFF_DELTA, ws + OFF_XC, ws + OFF_BM, ws + OFF_CM,
        ws + OFF_Z, A_log, D_param, ws + OFF_HIN, ws + OFF_YSUM);

    k6_head<<<BATCH, 256, 0, stream>>>(
        ws + OFF_YSUM, ws + OFF_XBAR, out_proj_w,
        out_fc_w, out_fc_b, mu_w, mu_b, sigma_w, sigma_b, out);
}

// Round 2
// 470.778 us; speedup vs baseline: 2.1411x; 2.1411x over previous
//
#include <hip/hip_runtime.h>
#include <math.h>

#define BATCH 16
#define SEQLEN 4096
#define D_MODEL 96
#define D_STATE 6
#define D_CONV 9
#define D_INNER 192
#define DT_RANK 6
#define NPOS (BATCH * SEQLEN)

#define NC 32            // chunks per sequence
#define CT (SEQLEN / NC) // 128 steps per chunk

// workspace layout (in floats)
#define OFF_XS    0L
#define OFF_Z     (OFF_XS    + (long)NPOS * D_INNER)
#define OFF_XC    (OFF_Z     + (long)NPOS * D_INNER)
#define OFF_DELTA (OFF_XC    + (long)NPOS * D_INNER)
#define OFF_BM    (OFF_DELTA + (long)NPOS * D_INNER)
#define OFF_CM    (OFF_BM    + (long)NPOS * D_STATE)
#define OFF_AC    (OFF_CM    + (long)NPOS * D_STATE)
#define OFF_BC    (OFF_AC    + (long)BATCH * D_INNER * NC * D_STATE)
#define OFF_HIN   (OFF_BC    + (long)BATCH * D_INNER * NC * D_STATE)
#define OFF_YSUM  (OFF_HIN   + (long)BATCH * D_INNER * NC * D_STATE)
#define OFF_XBAR  (OFF_YSUM  + (long)BATCH * D_INNER * NC)

__device__ __forceinline__ float siluf(float v) {
    return v / (1.0f + expf(-v));
}
__device__ __forceinline__ float softplusf(float v) {
    return (v > 20.0f) ? v : log1pf(expf(v));
}
__device__ __forceinline__ float eluf(float v) {
    return (v > 0.0f) ? v : expm1f(v);
}

// ---------------------------------------------------------------------------
// K1: RMSNorm + in_proj (h @ W^T -> xs, z), plus xbar (sum of raw x over L)
// block: 256 threads, 64 positions per block.
// W staged in LDS in K-chunks of 16 (pad 17 -> lane jg groups hit distinct
// banks: (12*17*g)%32 = 12g%32 distinct for g=0..7). acc[12][8] kept in VGPRs
// via __launch_bounds__(256,2) (VGPR cap 256 — round-1's cap of 64 spilled it).
// ---------------------------------------------------------------------------
#define TP1 64
#define HSTR 65   // hT row stride: (d*65+p)%32 varies with d -> conflict-free staging
__global__ __launch_bounds__(256, 2) void k1_rmsnorm_inproj(
    const float* __restrict__ x, const float* __restrict__ W,
    const float* __restrict__ norm_w,
    float* __restrict__ xs, float* __restrict__ z, float* __restrict__ xbar)
{
    __shared__ float hT[96 * HSTR];   // ~25 KB, [d][p]
    __shared__ float Wl[384 * 17];    // ~26 KB, K-chunk of W, [j][dk] pad 17
    __shared__ float scale[TP1];
    const int tid = threadIdx.x;
    const long p0 = (long)blockIdx.x * TP1;
    const int b = (int)(p0 / SEQLEN);

    // load x tile transposed into LDS (global reads fully coalesced)
    for (int i = tid; i < TP1 * 96; i += 256) {
        int p = i / 96, d = i - p * 96;
        hT[d * HSTR + p] = x[(p0 + p) * 96 + d];
    }
    __syncthreads();

    if (tid < TP1) {
        float ss = 0.0f;
        for (int d = 0; d < 96; d++) { float v = hT[d * HSTR + tid]; ss += v * v; }
        scale[tid] = 1.0f / sqrtf(ss / 96.0f + 1e-5f);
    } else if (tid < TP1 + 96) {
        int d = tid - TP1;
        float s = 0.0f;
        for (int p = 0; p < TP1; p++) s += hT[d * HSTR + p];
        atomicAdd(&xbar[b * 96 + d], s);   // xbar sums RAW x (pre-norm)
    }
    __syncthreads();

    // normalize in place
    for (int i = tid; i < TP1 * 96; i += 256) {
        int d = i >> 6, p = i & 63;
        hT[d * HSTR + p] *= scale[p] * norm_w[d];
    }

    // thread tile: 12 j x 8 p.  jg = tid>>3 (wave-contiguous j range), pg = tid&7
    const int jg = tid >> 3, pg = tid & 7;
    const int j0 = jg * 12, pbase = pg * 8;
    float acc[12][8];
#pragma unroll
    for (int jj = 0; jj < 12; jj++)
#pragma unroll
        for (int p = 0; p < 8; p++) acc[jj][p] = 0.0f;

    for (int dc = 0; dc < 6; dc++) {
        __syncthreads();   // protect Wl from previous chunk's readers
        // stage W[:, dc*16 .. dc*16+16) into LDS
        for (int i = tid; i < 384 * 16; i += 256) {
            int j = i >> 4, dk = i & 15;
            Wl[j * 17 + dk] = W[j * 96 + dc * 16 + dk];
        }
        __syncthreads();
#pragma unroll 4
        for (int dk = 0; dk < 16; dk++) {
            const int d = dc * 16 + dk;
            float hv[8];
#pragma unroll
            for (int p = 0; p < 8; p++) hv[p] = hT[d * HSTR + pbase + p];
#pragma unroll
            for (int jj = 0; jj < 12; jj++) {
                float wv = Wl[(j0 + jj) * 17 + dk];
#pragma unroll
                for (int p = 0; p < 8; p++) acc[jj][p] += wv * hv[p];
            }
        }
    }

    // store: jg<16 -> xs, else z (wave-uniform branch). float4 stores, 16B aligned.
    float* dst = (j0 < 192) ? xs : z;
    const int jc0 = (j0 < 192) ? j0 : j0 - 192;
#pragma unroll
    for (int p = 0; p < 8; p++) {
        long pos = p0 + pbase + p;
        float4* dp = (float4*)&dst[pos * D_INNER + jc0];
#pragma unroll
        for (int q = 0; q < 3; q++) {
            float4 v;
            v.x = acc[q * 4 + 0][p]; v.y = acc[q * 4 + 1][p];
            v.z = acc[q * 4 + 2][p]; v.w = acc[q * 4 + 3][p];
            dp[q] = v;
        }
    }
}

// ---------------------------------------------------------------------------
// K2: causal depthwise conv(9) + silu -> xc;  dbc = xc @ x_proj_w^T;
//     delta = softplus(delta_r @ dt_proj_w^T + dt_b);  store Bm, Cm
// block: 192 threads (one per channel e), 32 positions per block.
// x_proj_w staged in LDS (pad 193 -> f-groups hit distinct banks).
// ---------------------------------------------------------------------------
#define TP2 32
#define XSTR 193
__global__ __launch_bounds__(192) void k2_conv_proj(
    const float* __restrict__ xs,
    const float* __restrict__ conv_w, const float* __restrict__ conv_b,
    const float* __restrict__ x_proj_w,
    const float* __restrict__ dt_w, const float* __restrict__ dt_b,
    float* __restrict__ xc_out, float* __restrict__ delta_out,
    float* __restrict__ Bm_out, float* __restrict__ Cm_out)
{
    __shared__ float sxc[TP2 * XSTR];                    // ~24.7 KB
    __shared__ float sxp[18 * XSTR];                     // ~13.9 KB
    __shared__ float sdbc[TP2][DT_RANK + 2 * D_STATE];
    const int e = threadIdx.x;
    const long p0 = (long)blockIdx.x * TP2;
    const int b = (int)(p0 / SEQLEN);
    const int l0 = (int)(p0 % SEQLEN);
    const long brow = (long)b * SEQLEN;

    // stage x_proj_w (18x192) into LDS with bank-breaking pad
    for (int i = e; i < 18 * 192; i += 192) {
        int f = i / 192, kk = i - f * 192;
        sxp[f * XSTR + kk] = x_proj_w[i];
    }

    float cw[D_CONV];
#pragma unroll
    for (int k = 0; k < D_CONV; k++) cw[k] = conv_w[e * D_CONV + k];
    const float cb = conv_b[e];

    // rolling window over the causal conv
    float win[D_CONV];
#pragma unroll
    for (int k = 0; k < 8; k++) {
        int ll = l0 - 8 + k;
        win[k] = (ll >= 0) ? xs[(brow + ll) * D_INNER + e] : 0.0f;
    }
    for (int r = 0; r < TP2; r++) {
        win[8] = xs[(brow + l0 + r) * D_INNER + e];
        float s = cb;
#pragma unroll
        for (int k = 0; k < D_CONV; k++) s += win[k] * cw[k];
        float xcv = siluf(s);
        sxc[r * XSTR + e] = xcv;
        xc_out[(brow + l0 + r) * D_INNER + e] = xcv;
#pragma unroll
        for (int k = 0; k < 8; k++) win[k] = win[k + 1];
    }
    __syncthreads();

    // dbc: 32 positions x 18 outputs, each a 192-dot (all operands in LDS)
    for (int t = e; t < TP2 * 18; t += 192) {
        int p = t / 18, f = t - p * 18;
        const float* wrow = &sxp[f * XSTR];
        const float* xrow = &sxc[p * XSTR];
        float s = 0.0f;
#pragma unroll 4
        for (int kk = 0; kk < D_INNER; kk++) s += xrow[kk] * wrow[kk];
        sdbc[p][f] = s;
        long pos = brow + l0 + p;
        if (f >= 6 && f < 12)      Bm_out[pos * D_STATE + (f - 6)] = s;
        else if (f >= 12)          Cm_out[pos * D_STATE + (f - 12)] = s;
    }
    __syncthreads();

    // delta[e] = softplus(delta_r . dt_w[e,:] + dt_b[e])
    float dtw[DT_RANK];
#pragma unroll
    for (int q = 0; q < DT_RANK; q++) dtw[q] = dt_w[e * DT_RANK + q];
    const float dtb = dt_b[e];
    for (int r = 0; r < TP2; r++) {
        float s = dtb;
#pragma unroll
        for (int q = 0; q < DT_RANK; q++) s += sdbc[r][q] * dtw[q];
        delta_out[(brow + l0 + r) * D_INNER + e] = softplusf(s);
    }
}

// ---------------------------------------------------------------------------
// K3: scan pass A — per (b, e, chunk): cumulative product P and zero-init
// state S over CT steps. block: 192 threads (e), grid: B*NC
// ---------------------------------------------------------------------------
__global__ __launch_bounds__(192) void k3_scanA(
    const float* __restrict__ delta, const float* __restrict__ xc,
    const float* __restrict__ Bm, const float* __restrict__ A_log,
    float* __restrict__ Ac, float* __restrict__ Bc)
{
    const int e = threadIdx.x;
    const int c = blockIdx.x & (NC - 1);
    const int b = blockIdx.x >> 5;
    const long base = (long)b * SEQLEN + (long)c * CT;

    float a[D_STATE];
#pragma unroll
    for (int n = 0; n < D_STATE; n++) a[n] = -expf(A_log[e * D_STATE + n]);

    float P[D_STATE], S[D_STATE];
#pragma unroll
    for (int n = 0; n < D_STATE; n++) { P[n] = 1.0f; S[n] = 0.0f; }

    for (int t = 0; t < CT; t++) {
        long pos = base + t;
        float dl = delta[pos * D_INNER + e];
        float xv = xc[pos * D_INNER + e];
        float dx = dl * xv;
        float bm[D_STATE];
#pragma unroll
        for (int n = 0; n < D_STATE; n++) bm[n] = Bm[pos * D_STATE + n];
#pragma unroll
        for (int n = 0; n < D_STATE; n++) {
            float dA = expf(dl * a[n]);
            S[n] = dA * S[n] + dx * bm[n];
            P[n] *= dA;
        }
    }
    long o = (((long)b * D_INNER + e) * NC + c) * D_STATE;
#pragma unroll
    for (int n = 0; n < D_STATE; n++) { Ac[o + n] = P[n]; Bc[o + n] = S[n]; }
}

// ---------------------------------------------------------------------------
// K4: sequential chunk combine — per (b,e): Hin[c+1] = Ac[c]*Hin[c] + Bc[c]
// ---------------------------------------------------------------------------
__global__ __launch_bounds__(256) void k4_combine(
    const float* __restrict__ Ac, const float* __restrict__ Bc,
    float* __restrict__ Hin)
{
    int idx = blockIdx.x * 256 + threadIdx.x; // (b*192 + e)
    if (idx >= BATCH * D_INNER) return;
    float H[D_STATE];
#pragma unroll
    for (int n = 0; n < D_STATE; n++) H[n] = 0.0f;
    long base = (long)idx * NC * D_STATE;
    for (int c = 0; c < NC; c++) {
        long o = base + (long)c * D_STATE;
#pragma unroll
        for (int n = 0; n < D_STATE; n++) {
            Hin[o + n] = H[n];
            H[n] = Ac[o + n] * H[n] + Bc[o + n];
        }
    }
}

// ---------------------------------------------------------------------------
// K5: scan pass B — replay chunk with correct carry-in; emit per-chunk
// y-sums:  y = (h . Cm + D*xc) * silu(z), accumulated over the chunk
// ---------------------------------------------------------------------------
__global__ __launch_bounds__(192) void k5_scanB(
    const float* __restrict__ delta, const float* __restrict__ xc,
    const float* __restrict__ Bm, const float* __restrict__ Cm,
    const float* __restrict__ z, const float* __restrict__ A_log,
    const float* __restrict__ D_param, const float* __restrict__ Hin,
    float* __restrict__ ysum_part)
{
    const int e = threadIdx.x;
    const int c = blockIdx.x & (NC - 1);
    const int b = blockIdx.x >> 5;
    const long base = (long)b * SEQLEN + (long)c * CT;

    float a[D_STATE];
#pragma unroll
    for (int n = 0; n < D_STATE; n++) a[n] = -expf(A_log[e * D_STATE + n]);
    const float Dv = D_param[e];

    long ho = (((long)b * D_INNER + e) * NC + c) * D_STATE;
    float S[D_STATE];
#pragma unroll
    for (int n = 0; n < D_STATE; n++) S[n] = Hin[ho + n];

    float ysum = 0.0f;
    for (int t = 0; t < CT; t++) {
        long pos = base + t;
        float dl = delta[pos * D_INNER + e];
        float xv = xc[pos * D_INNER + e];
        float zv = z[pos * D_INNER + e];
        float dx = dl * xv;
        float y = 0.0f;
#pragma unroll
        for (int n = 0; n < D_STATE; n++) {
            float dA = expf(dl * a[n]);
            S[n] = dA * S[n] + dx * Bm[pos * D_STATE + n];
            y += S[n] * Cm[pos * D_STATE + n];
        }
        y += Dv * xv;
        y *= siluf(zv);
        ysum += y;
    }
    ysum_part[((long)b * D_INNER + e) * NC + c] = ysum;
}

// ---------------------------------------------------------------------------
// K6: output head — one block per batch element.
// ---------------------------------------------------------------------------
__global__ __launch_bounds__(256) void k6_head(
    const float* __restrict__ ysum_part, const float* __restrict__ xbar,
    const float* __restrict__ Wout,
    const float* __restrict__ fc_w, const float* __restrict__ fc_b,
    const float* __restrict__ mu_w, const float* __restrict__ mu_b,
    const float* __restrict__ sg_w, const float* __restrict__ sg_b,
    float* __restrict__ out)
{
    __shared__ float ybar[D_INNER];
    __shared__ float evec[D_MODEL];
    __shared__ float feat_s[64];
    const int b = blockIdx.x;
    const int tid = threadIdx.x;

    if (tid < D_INNER) {
        float s = 0.0f;
        long o = ((long)b * D_INNER + tid) * NC;
        for (int c = 0; c < NC; c++) s += ysum_part[o + c];
        ybar[tid] = s;
    }
    __syncthreads();

    if (tid < D_MODEL) {
        float s = xbar[b * D_MODEL + tid];
        const float* wrow = &Wout[tid * D_INNER];
        for (int e2 = 0; e2 < D_INNER; e2++) s += ybar[e2] * wrow[e2];
        evec[tid] = s / (float)SEQLEN;
    }
    __syncthreads();

    if (tid < 64) {
        float s = fc_b[tid];
        const float* wrow = &fc_w[tid * D_MODEL];
        for (int d = 0; d < D_MODEL; d++) s += evec[d] * wrow[d];
        float f = eluf(tanhf(s));
        feat_s[tid] = f;
        out[b * 64 + tid] = f; // feat
    }
    __syncthreads();

    if (tid < 64) {
        float smu = mu_b[tid], ssg = sg_b[tid];
        const float* mrow = &mu_w[tid * 64];
        const float* srow = &sg_w[tid * 64];
        for (int i = 0; i < 64; i++) {
            smu += feat_s[i] * mrow[i];
            ssg += feat_s[i] * srow[i];
        }
        out[1024 + b * 64 + tid] = smu;                        // mu
        out[2048 + b * 64 + tid] = eluf(ssg) + 1.0f + 1e-14f;  // sigma
    }
}

extern "C" void kernel_launch(void* const* d_in, const int* in_sizes, int n_in,
                              void* d_out, int out_size, void* d_ws, size_t ws_size,
                              hipStream_t stream) {
    const float* x         = (const float*)d_in[0];
    const float* in_proj_w = (const float*)d_in[1];
    const float* conv_w    = (const float*)d_in[2];
    const float* conv_b    = (const float*)d_in[3];
    const float* x_proj_w  = (const float*)d_in[4];
    const float* dt_proj_w = (const float*)d_in[5];
    const float* dt_proj_b = (const float*)d_in[6];
    const float* A_log     = (const float*)d_in[7];
    const float* D_param   = (const float*)d_in[8];
    const float* out_proj_w= (const float*)d_in[9];
    const float* norm_w    = (const float*)d_in[10];
    const float* out_fc_w  = (const float*)d_in[11];
    const float* out_fc_b  = (const float*)d_in[12];
    const float* mu_w      = (const float*)d_in[13];
    const float* mu_b      = (const float*)d_in[14];
    const float* sigma_w   = (const float*)d_in[15];
    const float* sigma_b   = (const float*)d_in[16];
    float* ws = (float*)d_ws;
    float* out = (float*)d_out;

    // zero xbar accumulator (atomicAdd target)
    hipMemsetAsync(ws + OFF_XBAR, 0, BATCH * D_MODEL * sizeof(float), stream);

    k1_rmsnorm_inproj<<<NPOS / TP1, 256, 0, stream>>>(
        x, in_proj_w, norm_w, ws + OFF_XS, ws + OFF_Z, ws + OFF_XBAR);

    k2_conv_proj<<<NPOS / TP2, 192, 0, stream>>>(
        ws + OFF_XS, conv_w, conv_b, x_proj_w, dt_proj_w, dt_proj_b,
        ws + OFF_XC, ws + OFF_DELTA, ws + OFF_BM, ws + OFF_CM);

    k3_scanA<<<BATCH * NC, 192, 0, stream>>>(
        ws + OFF_DELTA, ws + OFF_XC, ws + OFF_BM, A_log,
        ws + OFF_AC, ws + OFF_BC);

    k4_combine<<<(BATCH * D_INNER + 255) / 256, 256, 0, stream>>>(
        ws + OFF_AC, ws + OFF_BC, ws + OFF_HIN);

    k5_scanB<<<BATCH * NC, 192, 0, stream>>>(
        ws + OFF_DELTA, ws + OFF_XC, ws + OFF_BM, ws + OFF_CM,
        ws + OFF_Z, A_log, D_param, ws + OFF_HIN, ws + OFF_YSUM);

    k6_head<<<BATCH, 256, 0, stream>>>(
        ws + OFF_YSUM, ws + OFF_XBAR, out_proj_w,
        out_fc_w, out_fc_b, mu_w, mu_b, sigma_w, sigma_b, out);
}

// Round 3
// 442.728 us; speedup vs baseline: 2.2768x; 1.0634x over previous
//
#include <hip/hip_runtime.h>
#include <math.h>

#define BATCH 16
#define SEQLEN 4096
#define D_MODEL 96
#define D_STATE 6
#define D_CONV 9
#define D_INNER 192
#define DT_RANK 6
#define NPOS (BATCH * SEQLEN)

#define NC 64            // chunks per sequence
#define CT (SEQLEN / NC) // 64 steps per chunk

// workspace layout (in floats)
#define OFF_XS    0L
#define OFF_Z     (OFF_XS    + (long)NPOS * D_INNER)
#define OFF_DXC   (OFF_Z     + (long)NPOS * D_INNER)          // float2 {delta, xc}
#define OFF_BM    (OFF_DXC   + (long)NPOS * D_INNER * 2)
#define OFF_CM    (OFF_BM    + (long)NPOS * D_STATE)
#define OFF_AC    (OFF_CM    + (long)NPOS * D_STATE)
#define OFF_BC    (OFF_AC    + (long)BATCH * D_INNER * NC * D_STATE)
#define OFF_HIN   (OFF_BC    + (long)BATCH * D_INNER * NC * D_STATE)
#define OFF_YSUM  (OFF_HIN   + (long)BATCH * D_INNER * NC * D_STATE)
#define OFF_XBAR  (OFF_YSUM  + (long)BATCH * D_INNER * NC)

__device__ __forceinline__ float siluf(float v) {
    return v / (1.0f + expf(-v));
}
__device__ __forceinline__ float softplusf(float v) {
    return (v > 20.0f) ? v : log1pf(expf(v));
}
__device__ __forceinline__ float eluf(float v) {
    return (v > 0.0f) ? v : expm1f(v);
}

// ---------------------------------------------------------------------------
// K1: RMSNorm + in_proj (h @ W^T -> xs, z), plus xbar (sum of raw x over L)
// 256 threads, 64 positions per block. HSTR=68 (mult of 4 -> 16B-aligned
// ds_read_b128 on hv; bank shift 4/row). W staged [dk][j]-major, stride 392
// (j0=jg*12 -> 12jg%32 all distinct -> conflict-free b128 reads).
// ---------------------------------------------------------------------------
#define TP1 64
#define HSTR 68
#define WSTR 392
__global__ __launch_bounds__(256, 2) void k1_rmsnorm_inproj(
    const float* __restrict__ x, const float* __restrict__ W,
    const float* __restrict__ norm_w,
    float* __restrict__ xs, float* __restrict__ z, float* __restrict__ xbar)
{
    __shared__ float hT[96 * HSTR];    // 26.1 KB, [d][p]
    __shared__ float Wl[16 * WSTR];    // 25.1 KB, K-chunk of W, [dk][j]
    __shared__ float scale[TP1];
    const int tid = threadIdx.x;
    const long p0 = (long)blockIdx.x * TP1;
    const int b = (int)(p0 / SEQLEN);

    // load x tile transposed into LDS (global reads fully coalesced)
    for (int i = tid; i < TP1 * 96; i += 256) {
        int p = i / 96, d = i - p * 96;
        hT[d * HSTR + p] = x[(p0 + p) * 96 + d];
    }
    __syncthreads();

    if (tid < TP1) {
        float ss = 0.0f;
        for (int d = 0; d < 96; d++) { float v = hT[d * HSTR + tid]; ss += v * v; }
        scale[tid] = 1.0f / sqrtf(ss / 96.0f + 1e-5f);
    } else if (tid < TP1 + 96) {
        int d = tid - TP1;
        float s = 0.0f;
        for (int p = 0; p < TP1; p++) s += hT[d * HSTR + p];
        atomicAdd(&xbar[b * 96 + d], s);   // xbar sums RAW x (pre-norm)
    }
    __syncthreads();

    // normalize in place
    for (int i = tid; i < TP1 * 96; i += 256) {
        int d = i >> 6, p = i & 63;
        hT[d * HSTR + p] *= scale[p] * norm_w[d];
    }

    // thread tile: 12 j x 8 p.  jg = tid>>3, pg = tid&7
    const int jg = tid >> 3, pg = tid & 7;
    const int j0 = jg * 12, pbase = pg * 8;
    float acc[12][8];
#pragma unroll
    for (int jj = 0; jj < 12; jj++)
#pragma unroll
        for (int p = 0; p < 8; p++) acc[jj][p] = 0.0f;

    for (int dc = 0; dc < 6; dc++) {
        __syncthreads();   // protect Wl from previous chunk's readers (and hT on dc=0)
        // stage W[:, dc*16 .. +16) into LDS, [dk][j] layout; global reads coalesced
        for (int i = tid; i < 384 * 16; i += 256) {
            int dk = i & 15, j = i >> 4;
            Wl[dk * WSTR + j] = W[j * 96 + dc * 16 + dk];
        }
        __syncthreads();
#pragma unroll 4
        for (int dk = 0; dk < 16; dk++) {
            const int d = dc * 16 + dk;
            const float4* hp = (const float4*)&hT[d * HSTR + pbase];
            float4 h0 = hp[0], h1 = hp[1];
            float hv[8] = {h0.x, h0.y, h0.z, h0.w, h1.x, h1.y, h1.z, h1.w};
            const float4* wp = (const float4*)&Wl[dk * WSTR + j0];
            float4 w0 = wp[0], w1 = wp[1], w2 = wp[2];
            float wv[12] = {w0.x, w0.y, w0.z, w0.w, w1.x, w1.y, w1.z, w1.w,
                            w2.x, w2.y, w2.z, w2.w};
#pragma unroll
            for (int jj = 0; jj < 12; jj++)
#pragma unroll
                for (int p = 0; p < 8; p++) acc[jj][p] += wv[jj] * hv[p];
        }
    }

    // store: jg<16 -> xs, else z (wave-uniform). float4 stores, 16B aligned.
    float* dst = (j0 < 192) ? xs : z;
    const int jc0 = (j0 < 192) ? j0 : j0 - 192;
#pragma unroll
    for (int p = 0; p < 8; p++) {
        long pos = p0 + pbase + p;
        float4* dp = (float4*)&dst[pos * D_INNER + jc0];
#pragma unroll
        for (int q = 0; q < 3; q++) {
            float4 v;
            v.x = acc[q * 4 + 0][p]; v.y = acc[q * 4 + 1][p];
            v.z = acc[q * 4 + 2][p]; v.w = acc[q * 4 + 3][p];
            dp[q] = v;
        }
    }
}

// ---------------------------------------------------------------------------
// K2: causal depthwise conv(9)+silu -> xc; dbc = xc @ x_proj_w^T;
//     delta = softplus(...); writes interleaved {delta,xc} float2 + Bm/Cm.
// 192 threads, 32 positions/block. dbc retile: thread -> (p=e/6, fg=e%6),
// 3 outputs f in {fg, fg+6, fg+12}; inner loop 48x float4 (b128, conflict-free:
// w-row banks 4*fg distinct; xrow broadcast).
// ---------------------------------------------------------------------------
#define TP2 32
#define XSTR 196   // mult of 4 (16B-aligned rows), %32 = 4 -> bank spread
__global__ __launch_bounds__(192, 3) void k2_conv_proj(
    const float* __restrict__ xs,
    const float* __restrict__ conv_w, const float* __restrict__ conv_b,
    const float* __restrict__ x_proj_w,
    const float* __restrict__ dt_w, const float* __restrict__ dt_b,
    float2* __restrict__ dxc, float* __restrict__ Bm_out,
    float* __restrict__ Cm_out)
{
    __shared__ float sxc[TP2 * XSTR];                    // 25.1 KB
    __shared__ float sxp[18 * XSTR];                     // 14.1 KB
    __shared__ float sdbc[TP2][8];                       // delta_r columns only
    const int e = threadIdx.x;
    const long p0 = (long)blockIdx.x * TP2;
    const int b = (int)(p0 / SEQLEN);
    const int l0 = (int)(p0 % SEQLEN);
    const long brow = (long)b * SEQLEN;

    // stage x_proj_w (18x192) into LDS
    for (int i = e; i < 18 * 192; i += 192) {
        int f = i / 192, kk = i - f * 192;
        sxp[f * XSTR + kk] = x_proj_w[i];
    }

    float cw[D_CONV];
#pragma unroll
    for (int k = 0; k < D_CONV; k++) cw[k] = conv_w[e * D_CONV + k];
    const float cb = conv_b[e];

    // rolling-window causal conv
    float win[D_CONV];
#pragma unroll
    for (int k = 0; k < 8; k++) {
        int ll = l0 - 8 + k;
        win[k] = (ll >= 0) ? xs[(brow + ll) * D_INNER + e] : 0.0f;
    }
    for (int r = 0; r < TP2; r++) {
        win[8] = xs[(brow + l0 + r) * D_INNER + e];
        float s = cb;
#pragma unroll
        for (int k = 0; k < D_CONV; k++) s += win[k] * cw[k];
        sxc[r * XSTR + e] = siluf(s);
#pragma unroll
        for (int k = 0; k < 8; k++) win[k] = win[k + 1];
    }
    __syncthreads();

    // dbc: thread -> (p = e/6, fg = e%6); outputs f = fg, fg+6, fg+12
    {
        const int p = e / 6, fg = e - p * 6;
        const float4* xr = (const float4*)&sxc[p * XSTR];
        const float4* w0 = (const float4*)&sxp[fg * XSTR];
        const float4* w1 = (const float4*)&sxp[(fg + 6) * XSTR];
        const float4* w2 = (const float4*)&sxp[(fg + 12) * XSTR];
        float s0 = 0.0f, s1 = 0.0f, s2 = 0.0f;
#pragma unroll 4
        for (int kk = 0; kk < D_INNER / 4; kk++) {
            float4 xv = xr[kk];
            float4 a = w0[kk], bq = w1[kk], c = w2[kk];
            s0 += xv.x * a.x + xv.y * a.y + xv.z * a.z + xv.w * a.w;
            s1 += xv.x * bq.x + xv.y * bq.y + xv.z * bq.z + xv.w * bq.w;
            s2 += xv.x * c.x + xv.y * c.y + xv.z * c.z + xv.w * c.w;
        }
        sdbc[p][fg] = s0;
        // Bm/Cm stores: address (brow+l0)*6 + e -> contiguous across lanes
        Bm_out[(brow + l0 + p) * D_STATE + fg] = s1;
        Cm_out[(brow + l0 + p) * D_STATE + fg] = s2;
    }
    __syncthreads();

    // delta[e] = softplus(delta_r . dt_w[e,:] + dt_b[e]); write {delta, xc}
    float dtw[DT_RANK];
#pragma unroll
    for (int q = 0; q < DT_RANK; q++) dtw[q] = dt_w[e * DT_RANK + q];
    const float dtb = dt_b[e];
    for (int r = 0; r < TP2; r++) {
        float s = dtb;
#pragma unroll
        for (int q = 0; q < DT_RANK; q++) s += sdbc[r][q] * dtw[q];
        float2 v;
        v.x = softplusf(s);
        v.y = sxc[r * XSTR + e];
        dxc[(brow + l0 + r) * D_INNER + e] = v;
    }
}

// ---------------------------------------------------------------------------
// K3: scan pass A — per (b,e,chunk): cumulative product P, zero-init state S
// over CT steps. grid: B*NC, 192 threads (e).
// ---------------------------------------------------------------------------
__global__ __launch_bounds__(192, 3) void k3_scanA(
    const float2* __restrict__ dxc, const float* __restrict__ Bm,
    const float* __restrict__ A_log,
    float* __restrict__ Ac, float* __restrict__ Bc)
{
    const int e = threadIdx.x;
    const int c = blockIdx.x & (NC - 1);
    const int b = blockIdx.x >> 6;
    const long base = (long)b * SEQLEN + (long)c * CT;

    float a[D_STATE];
#pragma unroll
    for (int n = 0; n < D_STATE; n++) a[n] = -expf(A_log[e * D_STATE + n]);

    float P[D_STATE], S[D_STATE];
#pragma unroll
    for (int n = 0; n < D_STATE; n++) { P[n] = 1.0f; S[n] = 0.0f; }

#pragma unroll 4
    for (int t = 0; t < CT; t++) {
        long pos = base + t;
        float2 v = dxc[pos * D_INNER + e];
        float dl = v.x, xv = v.y;
        float dx = dl * xv;
        float bm[D_STATE];
#pragma unroll
        for (int n = 0; n < D_STATE; n++) bm[n] = Bm[pos * D_STATE + n];
#pragma unroll
        for (int n = 0; n < D_STATE; n++) {
            float dA = expf(dl * a[n]);
            S[n] = dA * S[n] + dx * bm[n];
            P[n] *= dA;
        }
    }
    long o = (((long)b * D_INNER + e) * NC + c) * D_STATE;
#pragma unroll
    for (int n = 0; n < D_STATE; n++) { Ac[o + n] = P[n]; Bc[o + n] = S[n]; }
}

// ---------------------------------------------------------------------------
// K4: sequential chunk combine — per (b,e): Hin[c+1] = Ac[c]*Hin[c] + Bc[c]
// ---------------------------------------------------------------------------
__global__ __launch_bounds__(256) void k4_combine(
    const float* __restrict__ Ac, const float* __restrict__ Bc,
    float* __restrict__ Hin)
{
    int idx = blockIdx.x * 256 + threadIdx.x; // (b*192 + e)
    if (idx >= BATCH * D_INNER) return;
    float H[D_STATE];
#pragma unroll
    for (int n = 0; n < D_STATE; n++) H[n] = 0.0f;
    long base = (long)idx * NC * D_STATE;
    for (int c = 0; c < NC; c++) {
        long o = base + (long)c * D_STATE;
#pragma unroll
        for (int n = 0; n < D_STATE; n++) {
            Hin[o + n] = H[n];
            H[n] = Ac[o + n] * H[n] + Bc[o + n];
        }
    }
}

// ---------------------------------------------------------------------------
// K5: scan pass B — replay chunk with carry-in; emit per-chunk y-sums:
// y = (h . Cm + D*xc) * silu(z), accumulated over the chunk.
// ---------------------------------------------------------------------------
__global__ __launch_bounds__(192, 3) void k5_scanB(
    const float2* __restrict__ dxc, const float* __restrict__ Bm,
    const float* __restrict__ Cm, const float* __restrict__ z,
    const float* __restrict__ A_log, const float* __restrict__ D_param,
    const float* __restrict__ Hin, float* __restrict__ ysum_part)
{
    const int e = threadIdx.x;
    const int c = blockIdx.x & (NC - 1);
    const int b = blockIdx.x >> 6;
    const long base = (long)b * SEQLEN + (long)c * CT;

    float a[D_STATE];
#pragma unroll
    for (int n = 0; n < D_STATE; n++) a[n] = -expf(A_log[e * D_STATE + n]);
    const float Dv = D_param[e];

    long ho = (((long)b * D_INNER + e) * NC + c) * D_STATE;
    float S[D_STATE];
#pragma unroll
    for (int n = 0; n < D_STATE; n++) S[n] = Hin[ho + n];

    float ysum = 0.0f;
#pragma unroll 4
    for (int t = 0; t < CT; t++) {
        long pos = base + t;
        float2 v = dxc[pos * D_INNER + e];
        float dl = v.x, xv = v.y;
        float zv = z[pos * D_INNER + e];
        float dx = dl * xv;
        float y = 0.0f;
#pragma unroll
        for (int n = 0; n < D_STATE; n++) {
            float dA = expf(dl * a[n]);
            S[n] = dA * S[n] + dx * Bm[pos * D_STATE + n];
            y += S[n] * Cm[pos * D_STATE + n];
        }
        y += Dv * xv;
        y *= siluf(zv);
        ysum += y;
    }
    ysum_part[((long)b * D_INNER + e) * NC + c] = ysum;
}

// ---------------------------------------------------------------------------
// K6: output head — one block per batch element.
// ---------------------------------------------------------------------------
__global__ __launch_bounds__(256) void k6_head(
    const float* __restrict__ ysum_part, const float* __restrict__ xbar,
    const float* __restrict__ Wout,
    const float* __restrict__ fc_w, const float* __restrict__ fc_b,
    const float* __restrict__ mu_w, const float* __restrict__ mu_b,
    const float* __restrict__ sg_w, const float* __restrict__ sg_b,
    float* __restrict__ out)
{
    __shared__ float ybar[D_INNER];
    __shared__ float evec[D_MODEL];
    __shared__ float feat_s[64];
    const int b = blockIdx.x;
    const int tid = threadIdx.x;

    if (tid < D_INNER) {
        float s = 0.0f;
        long o = ((long)b * D_INNER + tid) * NC;
        for (int c = 0; c < NC; c++) s += ysum_part[o + c];
        ybar[tid] = s;
    }
    __syncthreads();

    if (tid < D_MODEL) {
        float s = xbar[b * D_MODEL + tid];
        const float* wrow = &Wout[tid * D_INNER];
        for (int e2 = 0; e2 < D_INNER; e2++) s += ybar[e2] * wrow[e2];
        evec[tid] = s / (float)SEQLEN;
    }
    __syncthreads();

    if (tid < 64) {
        float s = fc_b[tid];
        const float* wrow = &fc_w[tid * D_MODEL];
        for (int d = 0; d < D_MODEL; d++) s += evec[d] * wrow[d];
        float f = eluf(tanhf(s));
        feat_s[tid] = f;
        out[b * 64 + tid] = f; // feat
    }
    __syncthreads();

    if (tid < 64) {
        float smu = mu_b[tid], ssg = sg_b[tid];
        const float* mrow = &mu_w[tid * 64];
        const float* srow = &sg_w[tid * 64];
        for (int i = 0; i < 64; i++) {
            smu += feat_s[i] * mrow[i];
            ssg += feat_s[i] * srow[i];
        }
        out[1024 + b * 64 + tid] = smu;                        // mu
        out[2048 + b * 64 + tid] = eluf(ssg) + 1.0f + 1e-14f;  // sigma
    }
}

extern "C" void kernel_launch(void* const* d_in, const int* in_sizes, int n_in,
                              void* d_out, int out_size, void* d_ws, size_t ws_size,
                              hipStream_t stream) {
    const float* x         = (const float*)d_in[0];
    const float* in_proj_w = (const float*)d_in[1];
    const float* conv_w    = (const float*)d_in[2];
    const float* conv_b    = (const float*)d_in[3];
    const float* x_proj_w  = (const float*)d_in[4];
    const float* dt_proj_w = (const float*)d_in[5];
    const float* dt_proj_b = (const float*)d_in[6];
    const float* A_log     = (const float*)d_in[7];
    const float* D_param   = (const float*)d_in[8];
    const float* out_proj_w= (const float*)d_in[9];
    const float* norm_w    = (const float*)d_in[10];
    const float* out_fc_w  = (const float*)d_in[11];
    const float* out_fc_b  = (const float*)d_in[12];
    const float* mu_w      = (const float*)d_in[13];
    const float* mu_b      = (const float*)d_in[14];
    const float* sigma_w   = (const float*)d_in[15];
    const float* sigma_b   = (const float*)d_in[16];
    float* ws = (float*)d_ws;
    float* out = (float*)d_out;

    // zero xbar accumulator (atomicAdd target)
    hipMemsetAsync(ws + OFF_XBAR, 0, BATCH * D_MODEL * sizeof(float), stream);

    k1_rmsnorm_inproj<<<NPOS / TP1, 256, 0, stream>>>(
        x, in_proj_w, norm_w, ws + OFF_XS, ws + OFF_Z, ws + OFF_XBAR);

    k2_conv_proj<<<NPOS / TP2, 192, 0, stream>>>(
        ws + OFF_XS, conv_w, conv_b, x_proj_w, dt_proj_w, dt_proj_b,
        (float2*)(ws + OFF_DXC), ws + OFF_BM, ws + OFF_CM);

    k3_scanA<<<BATCH * NC, 192, 0, stream>>>(
        (const float2*)(ws + OFF_DXC), ws + OFF_BM, A_log,
        ws + OFF_AC, ws + OFF_BC);

    k4_combine<<<(BATCH * D_INNER + 255) / 256, 256, 0, stream>>>(
        ws + OFF_AC, ws + OFF_BC, ws + OFF_HIN);

    k5_scanB<<<BATCH * NC, 192, 0, stream>>>(
        (const float2*)(ws + OFF_DXC), ws + OFF_BM, ws + OFF_CM,
        ws + OFF_Z, A_log, D_param, ws + OFF_HIN, ws + OFF_YSUM);

    k6_head<<<BATCH, 256, 0, stream>>>(
        ws + OFF_YSUM, ws + OFF_XBAR, out_proj_w,
        out_fc_w, out_fc_b, mu_w, mu_b, sigma_w, sigma_b, out);
}

// Round 4
// 389.995 us; speedup vs baseline: 2.5847x; 1.1352x over previous
//
#include <hip/hip_runtime.h>
#include <math.h>

#define BATCH 16
#define SEQLEN 4096
#define D_MODEL 96
#define D_STATE 6
#define D_CONV 9
#define D_INNER 192
#define DT_RANK 6
#define NPOS (BATCH * SEQLEN)

#define NC2 64            // chunks per sequence
#define CT2 (SEQLEN / NC2) // 64 steps per chunk

// workspace layout (in floats)
#define OFF_XS    0L
#define OFF_Z     (OFF_XS   + (long)NPOS * D_INNER)
#define OFF_OUT4  (OFF_Z    + (long)NPOS * D_INNER)   // float4 planes: B*NC2*5*192 float4s
#define OFF_YBAR  (OFF_OUT4 + (long)BATCH * NC2 * 5 * 192 * 4)
#define OFF_XBAR  (OFF_YBAR + (long)BATCH * D_INNER)

__device__ __forceinline__ float siluf(float v) {
    return v / (1.0f + expf(-v));
}
__device__ __forceinline__ float softplusf(float v) {
    return (v > 20.0f) ? v : log1pf(expf(v));
}
__device__ __forceinline__ float eluf(float v) {
    return (v > 0.0f) ? v : expm1f(v);
}

// ---------------------------------------------------------------------------
// K1: RMSNorm + in_proj (h @ W^T -> xs, z), plus xbar (sum of raw x over L)
// (unchanged from round 3 — known-good; will be re-examined once it tops the
// profile)
// ---------------------------------------------------------------------------
#define TP1 64
#define HSTR 68
#define WSTR 392
__global__ __launch_bounds__(256, 2) void k1_rmsnorm_inproj(
    const float* __restrict__ x, const float* __restrict__ W,
    const float* __restrict__ norm_w,
    float* __restrict__ xs, float* __restrict__ z, float* __restrict__ xbar)
{
    __shared__ float hT[96 * HSTR];    // 26.1 KB, [d][p]
    __shared__ float Wl[16 * WSTR];    // 25.1 KB, K-chunk of W, [dk][j]
    __shared__ float scale[TP1];
    const int tid = threadIdx.x;
    const long p0 = (long)blockIdx.x * TP1;
    const int b = (int)(p0 / SEQLEN);

    for (int i = tid; i < TP1 * 96; i += 256) {
        int p = i / 96, d = i - p * 96;
        hT[d * HSTR + p] = x[(p0 + p) * 96 + d];
    }
    __syncthreads();

    if (tid < TP1) {
        float ss = 0.0f;
        for (int d = 0; d < 96; d++) { float v = hT[d * HSTR + tid]; ss += v * v; }
        scale[tid] = 1.0f / sqrtf(ss / 96.0f + 1e-5f);
    } else if (tid < TP1 + 96) {
        int d = tid - TP1;
        float s = 0.0f;
        for (int p = 0; p < TP1; p++) s += hT[d * HSTR + p];
        atomicAdd(&xbar[b * 96 + d], s);   // xbar sums RAW x (pre-norm)
    }
    __syncthreads();

    for (int i = tid; i < TP1 * 96; i += 256) {
        int d = i >> 6, p = i & 63;
        hT[d * HSTR + p] *= scale[p] * norm_w[d];
    }

    const int jg = tid >> 3, pg = tid & 7;
    const int j0 = jg * 12, pbase = pg * 8;
    float acc[12][8];
#pragma unroll
    for (int jj = 0; jj < 12; jj++)
#pragma unroll
        for (int p = 0; p < 8; p++) acc[jj][p] = 0.0f;

    for (int dc = 0; dc < 6; dc++) {
        __syncthreads();
        for (int i = tid; i < 384 * 16; i += 256) {
            int dk = i & 15, j = i >> 4;
            Wl[dk * WSTR + j] = W[j * 96 + dc * 16 + dk];
        }
        __syncthreads();
#pragma unroll 4
        for (int dk = 0; dk < 16; dk++) {
            const int d = dc * 16 + dk;
            const float4* hp = (const float4*)&hT[d * HSTR + pbase];
            float4 h0 = hp[0], h1 = hp[1];
            float hv[8] = {h0.x, h0.y, h0.z, h0.w, h1.x, h1.y, h1.z, h1.w};
            const float4* wp = (const float4*)&Wl[dk * WSTR + j0];
            float4 w0 = wp[0], w1 = wp[1], w2 = wp[2];
            float wv[12] = {w0.x, w0.y, w0.z, w0.w, w1.x, w1.y, w1.z, w1.w,
                            w2.x, w2.y, w2.z, w2.w};
#pragma unroll
            for (int jj = 0; jj < 12; jj++)
#pragma unroll
                for (int p = 0; p < 8; p++) acc[jj][p] += wv[jj] * hv[p];
        }
    }

    float* dst = (j0 < 192) ? xs : z;
    const int jc0 = (j0 < 192) ? j0 : j0 - 192;
#pragma unroll
    for (int p = 0; p < 8; p++) {
        long pos = p0 + pbase + p;
        float4* dp = (float4*)&dst[pos * D_INNER + jc0];
#pragma unroll
        for (int q = 0; q < 3; q++) {
            float4 v;
            v.x = acc[q * 4 + 0][p]; v.y = acc[q * 4 + 1][p];
            v.z = acc[q * 4 + 2][p]; v.w = acc[q * 4 + 3][p];
            dp[q] = v;
        }
    }
}

// ---------------------------------------------------------------------------
// K2F: fused conv+silu -> xc (LDS); dbc GEMM -> delta_r/Bm/Cm (LDS);
// delta=softplus; chunk-local scan pass A with the G-trick:
//   S_t = dA*S + dx*B (zero-init), P_t = prod dA,
//   ysum0 += silu(z)*(C.S_t + D*xc),  G[n] += silu(z)*P_t[n]*C_t[n]
// Final y-sum for the chunk = ysum0 + G . h_in  (h_in folded in k4).
// Writes 5 coalesced float4 planes per (b,c): {P, S, G, ysum0}.
// grid: B*NC2 blocks, 192 threads (e). LDS ~70 KB -> 2 blocks/CU.
// ---------------------------------------------------------------------------
#define XSTR2 196
__global__ __launch_bounds__(192, 2) void k2f_conv_scan(
    const float* __restrict__ xs, const float* __restrict__ z,
    const float* __restrict__ conv_w, const float* __restrict__ conv_b,
    const float* __restrict__ x_proj_w,
    const float* __restrict__ dt_w, const float* __restrict__ dt_b,
    const float* __restrict__ A_log, const float* __restrict__ D_param,
    float4* __restrict__ out4)
{
    __shared__ float sxc[CT2 * XSTR2];   // 50.2 KB xc tile [t][e]
    __shared__ float sxp[18 * XSTR2];    // 14.1 KB x_proj_w
    __shared__ float sMeta[CT2][24];     // 6 KB: [t][0:6)=delta_r, [8:14)=Bm, [16:22)=Cm
    const int e = threadIdx.x;
    const int c = blockIdx.x & (NC2 - 1);
    const int b = blockIdx.x >> 6;
    const int l0 = c * CT2;
    const long brow = (long)b * SEQLEN;

    // stage x_proj_w (18x192)
    for (int i = e; i < 18 * 192; i += 192) {
        int f = i / 192, kk = i - f * 192;
        sxp[f * XSTR2 + kk] = x_proj_w[i];
    }

    // conv + silu -> sxc
    float cw[D_CONV];
#pragma unroll
    for (int k = 0; k < D_CONV; k++) cw[k] = conv_w[e * D_CONV + k];
    const float cb = conv_b[e];
    float win[D_CONV];
#pragma unroll
    for (int k = 0; k < 8; k++) {
        int ll = l0 - 8 + k;
        win[k] = (ll >= 0) ? xs[(brow + ll) * D_INNER + e] : 0.0f;
    }
    for (int r = 0; r < CT2; r++) {
        win[8] = xs[(brow + l0 + r) * D_INNER + e];
        float s = cb;
#pragma unroll
        for (int k = 0; k < D_CONV; k++) s += win[k] * cw[k];
        sxc[r * XSTR2 + e] = siluf(s);
#pragma unroll
        for (int k = 0; k < 8; k++) win[k] = win[k + 1];
    }
    __syncthreads();

    // dbc GEMM: thread -> (p = e/3 in [0,64), fh = e%3); 6 outputs f = fh+3k
    {
        const int p = e / 3, fh = e - p * 3;
        const float4* xr = (const float4*)&sxc[p * XSTR2];
        const float4* w0 = (const float4*)&sxp[(fh     ) * XSTR2];
        const float4* w1 = (const float4*)&sxp[(fh +  3) * XSTR2];
        const float4* w2 = (const float4*)&sxp[(fh +  6) * XSTR2];
        const float4* w3 = (const float4*)&sxp[(fh +  9) * XSTR2];
        const float4* w4 = (const float4*)&sxp[(fh + 12) * XSTR2];
        const float4* w5 = (const float4*)&sxp[(fh + 15) * XSTR2];
        float s0=0,s1=0,s2=0,s3=0,s4=0,s5=0;
#pragma unroll 4
        for (int kk = 0; kk < D_INNER / 4; kk++) {
            float4 xv = xr[kk];
            float4 a0 = w0[kk], a1 = w1[kk], a2 = w2[kk];
            float4 a3 = w3[kk], a4 = w4[kk], a5 = w5[kk];
            s0 += xv.x*a0.x + xv.y*a0.y + xv.z*a0.z + xv.w*a0.w;
            s1 += xv.x*a1.x + xv.y*a1.y + xv.z*a1.z + xv.w*a1.w;
            s2 += xv.x*a2.x + xv.y*a2.y + xv.z*a2.z + xv.w*a2.w;
            s3 += xv.x*a3.x + xv.y*a3.y + xv.z*a3.z + xv.w*a3.w;
            s4 += xv.x*a4.x + xv.y*a4.y + xv.z*a4.z + xv.w*a4.w;
            s5 += xv.x*a5.x + xv.y*a5.y + xv.z*a5.z + xv.w*a5.w;
        }
        // f<6 -> col f (delta_r); f in [6,12) -> col f+2 (Bm); f>=12 -> col f+4 (Cm)
        sMeta[p][fh    ]     = s0;   // f = fh
        sMeta[p][fh + 3]     = s1;   // f = fh+3
        sMeta[p][fh + 8]     = s2;   // f = fh+6  -> Bm[fh]
        sMeta[p][fh + 11]    = s3;   // f = fh+9  -> Bm[fh+3]
        sMeta[p][fh + 16]    = s4;   // f = fh+12 -> Cm[fh]
        sMeta[p][fh + 19]    = s5;   // f = fh+15 -> Cm[fh+3]
    }
    __syncthreads();

    // chunk-local scan (pass A + G-trick)
    float a[D_STATE];
#pragma unroll
    for (int n = 0; n < D_STATE; n++) a[n] = -expf(A_log[e * D_STATE + n]);
    float dtw[DT_RANK];
#pragma unroll
    for (int q = 0; q < DT_RANK; q++) dtw[q] = dt_w[e * DT_RANK + q];
    const float dtb = dt_b[e];
    const float Dv = D_param[e];
    const float* zp = &z[(brow + l0) * D_INNER + e];

    float S[D_STATE], P[D_STATE], G[D_STATE];
#pragma unroll
    for (int n = 0; n < D_STATE; n++) { S[n] = 0.0f; P[n] = 1.0f; G[n] = 0.0f; }
    float ysum0 = 0.0f;

#pragma unroll 2
    for (int t = 0; t < CT2; t++) {
        float dr = dtb;
#pragma unroll
        for (int q = 0; q < DT_RANK; q++) dr += sMeta[t][q] * dtw[q];
        float dl = softplusf(dr);
        float xv = sxc[t * XSTR2 + e];
        float zw = siluf(zp[(long)t * D_INNER]);
        float dx = dl * xv;
        float y = Dv * xv;
#pragma unroll
        for (int n = 0; n < D_STATE; n++) {
            float dA = expf(dl * a[n]);
            S[n] = dA * S[n] + dx * sMeta[t][8 + n];
            P[n] *= dA;
            float cn = sMeta[t][16 + n];
            y += S[n] * cn;
            G[n] += zw * P[n] * cn;
        }
        ysum0 += zw * y;
    }

    // write 5 coalesced float4 planes: {P0-3},{P4,P5,S0,S1},{S2-5},{G0-3},{G4,G5,ysum0,0}
    long ob = (long)(b * NC2 + c) * 5 * 192 + e;
    float4 q0, q1, q2, q3, q4;
    q0.x=P[0]; q0.y=P[1]; q0.z=P[2]; q0.w=P[3];
    q1.x=P[4]; q1.y=P[5]; q1.z=S[0]; q1.w=S[1];
    q2.x=S[2]; q2.y=S[3]; q2.z=S[4]; q2.w=S[5];
    q3.x=G[0]; q3.y=G[1]; q3.z=G[2]; q3.w=G[3];
    q4.x=G[4]; q4.y=G[5]; q4.z=ysum0; q4.w=0.0f;
    out4[ob          ] = q0;
    out4[ob + 192    ] = q1;
    out4[ob + 2 * 192] = q2;
    out4[ob + 3 * 192] = q3;
    out4[ob + 4 * 192] = q4;
}

// ---------------------------------------------------------------------------
// K4C: per (b,e): walk chunks sequentially, fold carry-in:
//   ybar += ysum0[c] + G[c].H;  H = P[c]*H + S[c]
// grid: BATCH blocks x 192 threads. Reads the 5 planes coalesced.
// ---------------------------------------------------------------------------
__global__ __launch_bounds__(192) void k4_combine_y(
    const float4* __restrict__ out4, float* __restrict__ ybar)
{
    const int e = threadIdx.x;
    const int b = blockIdx.x;
    float H[D_STATE];
#pragma unroll
    for (int n = 0; n < D_STATE; n++) H[n] = 0.0f;
    float yb = 0.0f;
#pragma unroll 2
    for (int c = 0; c < NC2; c++) {
        long ob = (long)(b * NC2 + c) * 5 * 192 + e;
        float4 q0 = out4[ob];
        float4 q1 = out4[ob + 192];
        float4 q2 = out4[ob + 2 * 192];
        float4 q3 = out4[ob + 3 * 192];
        float4 q4 = out4[ob + 4 * 192];
        float Pv[6] = {q0.x, q0.y, q0.z, q0.w, q1.x, q1.y};
        float Sv[6] = {q1.z, q1.w, q2.x, q2.y, q2.z, q2.w};
        float Gv[6] = {q3.x, q3.y, q3.z, q3.w, q4.x, q4.y};
        float g = 0.0f;
#pragma unroll
        for (int n = 0; n < D_STATE; n++) g += Gv[n] * H[n];
        yb += q4.z + g;
#pragma unroll
        for (int n = 0; n < D_STATE; n++) H[n] = Pv[n] * H[n] + Sv[n];
    }
    ybar[b * D_INNER + e] = yb;
}

// ---------------------------------------------------------------------------
// K6: output head — one block per batch element; reads ybar directly.
// ---------------------------------------------------------------------------
__global__ __launch_bounds__(256) void k6_head(
    const float* __restrict__ ybar_g, const float* __restrict__ xbar,
    const float* __restrict__ Wout,
    const float* __restrict__ fc_w, const float* __restrict__ fc_b,
    const float* __restrict__ mu_w, const float* __restrict__ mu_b,
    const float* __restrict__ sg_w, const float* __restrict__ sg_b,
    float* __restrict__ out)
{
    __shared__ float ybar[D_INNER];
    __shared__ float evec[D_MODEL];
    __shared__ float feat_s[64];
    const int b = blockIdx.x;
    const int tid = threadIdx.x;

    if (tid < D_INNER) ybar[tid] = ybar_g[b * D_INNER + tid];
    __syncthreads();

    if (tid < D_MODEL) {
        float s = xbar[b * D_MODEL + tid];
        const float* wrow = &Wout[tid * D_INNER];
        for (int e2 = 0; e2 < D_INNER; e2++) s += ybar[e2] * wrow[e2];
        evec[tid] = s / (float)SEQLEN;
    }
    __syncthreads();

    if (tid < 64) {
        float s = fc_b[tid];
        const float* wrow = &fc_w[tid * D_MODEL];
        for (int d = 0; d < D_MODEL; d++) s += evec[d] * wrow[d];
        float f = eluf(tanhf(s));
        feat_s[tid] = f;
        out[b * 64 + tid] = f; // feat
    }
    __syncthreads();

    if (tid < 64) {
        float smu = mu_b[tid], ssg = sg_b[tid];
        const float* mrow = &mu_w[tid * 64];
        const float* srow = &sg_w[tid * 64];
        for (int i = 0; i < 64; i++) {
            smu += feat_s[i] * mrow[i];
            ssg += feat_s[i] * srow[i];
        }
        out[1024 + b * 64 + tid] = smu;                        // mu
        out[2048 + b * 64 + tid] = eluf(ssg) + 1.0f + 1e-14f;  // sigma
    }
}

extern "C" void kernel_launch(void* const* d_in, const int* in_sizes, int n_in,
                              void* d_out, int out_size, void* d_ws, size_t ws_size,
                              hipStream_t stream) {
    const float* x         = (const float*)d_in[0];
    const float* in_proj_w = (const float*)d_in[1];
    const float* conv_w    = (const float*)d_in[2];
    const float* conv_b    = (const float*)d_in[3];
    const float* x_proj_w  = (const float*)d_in[4];
    const float* dt_proj_w = (const float*)d_in[5];
    const float* dt_proj_b = (const float*)d_in[6];
    const float* A_log     = (const float*)d_in[7];
    const float* D_param   = (const float*)d_in[8];
    const float* out_proj_w= (const float*)d_in[9];
    const float* norm_w    = (const float*)d_in[10];
    const float* out_fc_w  = (const float*)d_in[11];
    const float* out_fc_b  = (const float*)d_in[12];
    const float* mu_w      = (const float*)d_in[13];
    const float* mu_b      = (const float*)d_in[14];
    const float* sigma_w   = (const float*)d_in[15];
    const float* sigma_b   = (const float*)d_in[16];
    float* ws = (float*)d_ws;
    float* out = (float*)d_out;

    // zero xbar accumulator (atomicAdd target)
    hipMemsetAsync(ws + OFF_XBAR, 0, BATCH * D_MODEL * sizeof(float), stream);

    k1_rmsnorm_inproj<<<NPOS / TP1, 256, 0, stream>>>(
        x, in_proj_w, norm_w, ws + OFF_XS, ws + OFF_Z, ws + OFF_XBAR);

    k2f_conv_scan<<<BATCH * NC2, 192, 0, stream>>>(
        ws + OFF_XS, ws + OFF_Z, conv_w, conv_b, x_proj_w,
        dt_proj_w, dt_proj_b, A_log, D_param,
        (float4*)(ws + OFF_OUT4));

    k4_combine_y<<<BATCH, 192, 0, stream>>>(
        (const float4*)(ws + OFF_OUT4), ws + OFF_YBAR);

    k6_head<<<BATCH, 256, 0, stream>>>(
        ws + OFF_YBAR, ws + OFF_XBAR, out_proj_w,
        out_fc_w, out_fc_b, mu_w, mu_b, sigma_w, sigma_b, out);
}

// Round 5
// 312.247 us; speedup vs baseline: 3.2282x; 1.2490x over previous
//
#include <hip/hip_runtime.h>
#include <math.h>

#define BATCH 16
#define SEQLEN 4096
#define D_MODEL 96
#define D_STATE 6
#define D_CONV 9
#define D_INNER 192
#define DT_RANK 6
#define NPOS (BATCH * SEQLEN)

#define NC2 128            // chunks per sequence
#define CT2 (SEQLEN / NC2) // 32 steps per chunk

// workspace layout (in floats)
#define OFF_XS    0L
#define OFF_Z     (OFF_XS   + (long)NPOS * D_INNER)
#define OFF_OUT4  (OFF_Z    + (long)NPOS * D_INNER)   // float4 planes: B*NC2*5*192 float4s
#define OFF_XBAR  (OFF_OUT4 + (long)BATCH * NC2 * 5 * 192 * 4)

// fast transcendentals (native v_exp_f32 / v_log_f32 / fast div).
// abs threshold is 2e-2 and current error 1.9e-6 -> ample headroom.
__device__ __forceinline__ float silu_fast(float v) {
    return __fdividef(v, 1.0f + __expf(-v));
}
__device__ __forceinline__ float softplus_fast(float v) {
    return (v > 20.0f) ? v : __logf(1.0f + __expf(v));
}
__device__ __forceinline__ float eluf(float v) {
    return (v > 0.0f) ? v : expm1f(v);
}

// ---------------------------------------------------------------------------
// K1: RMSNorm + in_proj (h @ W^T -> xs, z), plus xbar (sum of raw x over L)
// (unchanged from round 3)
// ---------------------------------------------------------------------------
#define TP1 64
#define HSTR 68
#define WSTR 392
__global__ __launch_bounds__(256, 2) void k1_rmsnorm_inproj(
    const float* __restrict__ x, const float* __restrict__ W,
    const float* __restrict__ norm_w,
    float* __restrict__ xs, float* __restrict__ z, float* __restrict__ xbar)
{
    __shared__ float hT[96 * HSTR];    // 26.1 KB, [d][p]
    __shared__ float Wl[16 * WSTR];    // 25.1 KB, K-chunk of W, [dk][j]
    __shared__ float scale[TP1];
    const int tid = threadIdx.x;
    const long p0 = (long)blockIdx.x * TP1;
    const int b = (int)(p0 / SEQLEN);

    for (int i = tid; i < TP1 * 96; i += 256) {
        int p = i / 96, d = i - p * 96;
        hT[d * HSTR + p] = x[(p0 + p) * 96 + d];
    }
    __syncthreads();

    if (tid < TP1) {
        float ss = 0.0f;
        for (int d = 0; d < 96; d++) { float v = hT[d * HSTR + tid]; ss += v * v; }
        scale[tid] = 1.0f / sqrtf(ss / 96.0f + 1e-5f);
    } else if (tid < TP1 + 96) {
        int d = tid - TP1;
        float s = 0.0f;
        for (int p = 0; p < TP1; p++) s += hT[d * HSTR + p];
        atomicAdd(&xbar[b * 96 + d], s);   // xbar sums RAW x (pre-norm)
    }
    __syncthreads();

    for (int i = tid; i < TP1 * 96; i += 256) {
        int d = i >> 6, p = i & 63;
        hT[d * HSTR + p] *= scale[p] * norm_w[d];
    }

    const int jg = tid >> 3, pg = tid & 7;
    const int j0 = jg * 12, pbase = pg * 8;
    float acc[12][8];
#pragma unroll
    for (int jj = 0; jj < 12; jj++)
#pragma unroll
        for (int p = 0; p < 8; p++) acc[jj][p] = 0.0f;

    for (int dc = 0; dc < 6; dc++) {
        __syncthreads();
        for (int i = tid; i < 384 * 16; i += 256) {
            int dk = i & 15, j = i >> 4;
            Wl[dk * WSTR + j] = W[j * 96 + dc * 16 + dk];
        }
        __syncthreads();
#pragma unroll 4
        for (int dk = 0; dk < 16; dk++) {
            const int d = dc * 16 + dk;
            const float4* hp = (const float4*)&hT[d * HSTR + pbase];
            float4 h0 = hp[0], h1 = hp[1];
            float hv[8] = {h0.x, h0.y, h0.z, h0.w, h1.x, h1.y, h1.z, h1.w};
            const float4* wp = (const float4*)&Wl[dk * WSTR + j0];
            float4 w0 = wp[0], w1 = wp[1], w2 = wp[2];
            float wv[12] = {w0.x, w0.y, w0.z, w0.w, w1.x, w1.y, w1.z, w1.w,
                            w2.x, w2.y, w2.z, w2.w};
#pragma unroll
            for (int jj = 0; jj < 12; jj++)
#pragma unroll
                for (int p = 0; p < 8; p++) acc[jj][p] += wv[jj] * hv[p];
        }
    }

    float* dst = (j0 < 192) ? xs : z;
    const int jc0 = (j0 < 192) ? j0 : j0 - 192;
#pragma unroll
    for (int p = 0; p < 8; p++) {
        long pos = p0 + pbase + p;
        float4* dp = (float4*)&dst[pos * D_INNER + jc0];
#pragma unroll
        for (int q = 0; q < 3; q++) {
            float4 v;
            v.x = acc[q * 4 + 0][p]; v.y = acc[q * 4 + 1][p];
            v.z = acc[q * 4 + 2][p]; v.w = acc[q * 4 + 3][p];
            dp[q] = v;
        }
    }
}

// ---------------------------------------------------------------------------
// K2F: fused conv+silu -> xc (LDS); dbc GEMM -> delta_r/Bm/Cm (packed LDS);
// chunk-local scan pass A with G-trick:
//   S_t = dA*S + dx*B (zero-init), P_t = prod dA,
//   ysum0 += silu(z)*(C.S_t + D*xc),  G[n] += silu(z)*P_t[n]*C_t[n]
// Writes 5 coalesced float4 planes per (b,c): {P, S, G, ysum0}.
// CT2=32 -> LDS 41.8 KB -> 3 blocks/CU; grid B*128 = 2048 blocks.
// ---------------------------------------------------------------------------
#define XSTR2 196
__global__ __launch_bounds__(192, 3) void k2f_conv_scan(
    const float* __restrict__ xs, const float* __restrict__ z,
    const float* __restrict__ conv_w, const float* __restrict__ conv_b,
    const float* __restrict__ x_proj_w,
    const float* __restrict__ dt_w, const float* __restrict__ dt_b,
    const float* __restrict__ A_log, const float* __restrict__ D_param,
    float4* __restrict__ out4)
{
    __shared__ float sxc[CT2 * XSTR2];   // 25.1 KB xc tile [t][e]
    __shared__ float sxp[18 * XSTR2];    // 14.1 KB x_proj_w
    __shared__ float sMeta[CT2][20];     // 2.5 KB: [0:6) dr, [8:14) Bm, [14:20) Cm
    const int e = threadIdx.x;
    const int c = blockIdx.x & (NC2 - 1);
    const int b = blockIdx.x >> 7;
    const int l0 = c * CT2;
    const long brow = (long)b * SEQLEN;

    // stage x_proj_w (18x192)
    for (int i = e; i < 18 * 192; i += 192) {
        int f = i / 192, kk = i - f * 192;
        sxp[f * XSTR2 + kk] = x_proj_w[i];
    }

    // conv + silu -> sxc
    float cw[D_CONV];
#pragma unroll
    for (int k = 0; k < D_CONV; k++) cw[k] = conv_w[e * D_CONV + k];
    const float cb = conv_b[e];
    float win[D_CONV];
#pragma unroll
    for (int k = 0; k < 8; k++) {
        int ll = l0 - 8 + k;
        win[k] = (ll >= 0) ? xs[(brow + ll) * D_INNER + e] : 0.0f;
    }
    for (int r = 0; r < CT2; r++) {
        win[8] = xs[(brow + l0 + r) * D_INNER + e];
        float s = cb;
#pragma unroll
        for (int k = 0; k < D_CONV; k++) s += win[k] * cw[k];
        sxc[r * XSTR2 + e] = silu_fast(s);
#pragma unroll
        for (int k = 0; k < 8; k++) win[k] = win[k + 1];
    }
    __syncthreads();

    // dbc GEMM: thread -> (p = e/6 in [0,32), fg = e%6); f = fg, fg+6, fg+12
    {
        const int p = e / 6, fg = e - p * 6;
        const float4* xr = (const float4*)&sxc[p * XSTR2];
        const float4* w0 = (const float4*)&sxp[fg * XSTR2];
        const float4* w1 = (const float4*)&sxp[(fg + 6) * XSTR2];
        const float4* w2 = (const float4*)&sxp[(fg + 12) * XSTR2];
        float s0 = 0.0f, s1 = 0.0f, s2 = 0.0f;
#pragma unroll 4
        for (int kk = 0; kk < D_INNER / 4; kk++) {
            float4 xv = xr[kk];
            float4 a = w0[kk], bq = w1[kk], cc = w2[kk];
            s0 += xv.x * a.x + xv.y * a.y + xv.z * a.z + xv.w * a.w;
            s1 += xv.x * bq.x + xv.y * bq.y + xv.z * bq.z + xv.w * bq.w;
            s2 += xv.x * cc.x + xv.y * cc.y + xv.z * cc.z + xv.w * cc.w;
        }
        sMeta[p][fg] = s0;          // delta_r[fg]
        sMeta[p][8 + fg] = s1;      // Bm[fg]
        sMeta[p][14 + fg] = s2;     // Cm[fg]
    }
    __syncthreads();

    // chunk-local scan (pass A + G-trick), fast transcendentals
    float a[D_STATE];
#pragma unroll
    for (int n = 0; n < D_STATE; n++) a[n] = -__expf(A_log[e * D_STATE + n]);
    float dtw[DT_RANK];
#pragma unroll
    for (int q = 0; q < DT_RANK; q++) dtw[q] = dt_w[e * DT_RANK + q];
    const float dtb = dt_b[e];
    const float Dv = D_param[e];
    const float* zp = &z[(brow + l0) * D_INNER + e];

    float S[D_STATE], P[D_STATE], G[D_STATE];
#pragma unroll
    for (int n = 0; n < D_STATE; n++) { S[n] = 0.0f; P[n] = 1.0f; G[n] = 0.0f; }
    float ysum0 = 0.0f;

#pragma unroll 2
    for (int t = 0; t < CT2; t++) {
        const float4* m4 = (const float4*)&sMeta[t][0];
        float4 m0 = m4[0];            // dr0-3
        float4 m1 = m4[1];            // dr4, dr5, junk, junk
        float4 mB0 = m4[2];           // B0-3
        float4 mB1 = m4[3];           // B4, B5, C0, C1
        float4 mC  = m4[4];           // C2-5
        float Bv[6] = {mB0.x, mB0.y, mB0.z, mB0.w, mB1.x, mB1.y};
        float Cv[6] = {mB1.z, mB1.w, mC.x, mC.y, mC.z, mC.w};
        float dr = dtb + m0.x * dtw[0] + m0.y * dtw[1] + m0.z * dtw[2]
                 + m0.w * dtw[3] + m1.x * dtw[4] + m1.y * dtw[5];
        float dl = softplus_fast(dr);
        float xv = sxc[t * XSTR2 + e];
        float zw = silu_fast(zp[(long)t * D_INNER]);
        float dx = dl * xv;
        float y = Dv * xv;
#pragma unroll
        for (int n = 0; n < D_STATE; n++) {
            float dA = __expf(dl * a[n]);
            S[n] = dA * S[n] + dx * Bv[n];
            P[n] *= dA;
            y += S[n] * Cv[n];
            G[n] += zw * P[n] * Cv[n];
        }
        ysum0 += zw * y;
    }

    // 5 coalesced float4 planes: {P0-3},{P4,P5,S0,S1},{S2-5},{G0-3},{G4,G5,ysum0,0}
    long ob = (long)(b * NC2 + c) * 5 * 192 + e;
    float4 q0, q1, q2, q3, q4;
    q0.x=P[0]; q0.y=P[1]; q0.z=P[2]; q0.w=P[3];
    q1.x=P[4]; q1.y=P[5]; q1.z=S[0]; q1.w=S[1];
    q2.x=S[2]; q2.y=S[3]; q2.z=S[4]; q2.w=S[5];
    q3.x=G[0]; q3.y=G[1]; q3.z=G[2]; q3.w=G[3];
    q4.x=G[4]; q4.y=G[5]; q4.z=ysum0; q4.w=0.0f;
    out4[ob          ] = q0;
    out4[ob + 192    ] = q1;
    out4[ob + 2 * 192] = q2;
    out4[ob + 3 * 192] = q3;
    out4[ob + 4 * 192] = q4;
}

// ---------------------------------------------------------------------------
// K4H: per-batch block: (1) walk 128 chunks folding carry-in ->
// ybar[e] in LDS; (2) output head (out_proj mean-fold, fc, mu, sigma).
// ---------------------------------------------------------------------------
__global__ __launch_bounds__(192) void k4_head(
    const float4* __restrict__ out4, const float* __restrict__ xbar,
    const float* __restrict__ Wout,
    const float* __restrict__ fc_w, const float* __restrict__ fc_b,
    const float* __restrict__ mu_w, const float* __restrict__ mu_b,
    const float* __restrict__ sg_w, const float* __restrict__ sg_b,
    float* __restrict__ out)
{
    __shared__ float ybar[D_INNER];
    __shared__ float evec[D_MODEL];
    __shared__ float feat_s[64];
    const int e = threadIdx.x;
    const int b = blockIdx.x;

    float H[D_STATE];
#pragma unroll
    for (int n = 0; n < D_STATE; n++) H[n] = 0.0f;
    float yb = 0.0f;
#pragma unroll 4
    for (int c = 0; c < NC2; c++) {
        long ob = (long)(b * NC2 + c) * 5 * 192 + e;
        float4 q0 = out4[ob];
        float4 q1 = out4[ob + 192];
        float4 q2 = out4[ob + 2 * 192];
        float4 q3 = out4[ob + 3 * 192];
        float4 q4 = out4[ob + 4 * 192];
        float Pv[6] = {q0.x, q0.y, q0.z, q0.w, q1.x, q1.y};
        float Sv[6] = {q1.z, q1.w, q2.x, q2.y, q2.z, q2.w};
        float Gv[6] = {q3.x, q3.y, q3.z, q3.w, q4.x, q4.y};
        float g = 0.0f;
#pragma unroll
        for (int n = 0; n < D_STATE; n++) g += Gv[n] * H[n];
        yb += q4.z + g;
#pragma unroll
        for (int n = 0; n < D_STATE; n++) H[n] = Pv[n] * H[n] + Sv[n];
    }
    ybar[e] = yb;
    __syncthreads();

    if (e < D_MODEL) {
        float s = xbar[b * D_MODEL + e];
        const float* wrow = &Wout[e * D_INNER];
        for (int e2 = 0; e2 < D_INNER; e2++) s += ybar[e2] * wrow[e2];
        evec[e] = s / (float)SEQLEN;
    }
    __syncthreads();

    if (e < 64) {
        float s = fc_b[e];
        const float* wrow = &fc_w[e * D_MODEL];
        for (int d = 0; d < D_MODEL; d++) s += evec[d] * wrow[d];
        float f = eluf(tanhf(s));
        feat_s[e] = f;
        out[b * 64 + e] = f; // feat
    }
    __syncthreads();

    if (e < 64) {
        float smu = mu_b[e], ssg = sg_b[e];
        const float* mrow = &mu_w[e * 64];
        const float* srow = &sg_w[e * 64];
        for (int i = 0; i < 64; i++) {
            smu += feat_s[i] * mrow[i];
            ssg += feat_s[i] * srow[i];
        }
        out[1024 + b * 64 + e] = smu;                        // mu
        out[2048 + b * 64 + e] = eluf(ssg) + 1.0f + 1e-14f;  // sigma
    }
}

extern "C" void kernel_launch(void* const* d_in, const int* in_sizes, int n_in,
                              void* d_out, int out_size, void* d_ws, size_t ws_size,
                              hipStream_t stream) {
    const float* x         = (const float*)d_in[0];
    const float* in_proj_w = (const float*)d_in[1];
    const float* conv_w    = (const float*)d_in[2];
    const float* conv_b    = (const float*)d_in[3];
    const float* x_proj_w  = (const float*)d_in[4];
    const float* dt_proj_w = (const float*)d_in[5];
    const float* dt_proj_b = (const float*)d_in[6];
    const float* A_log     = (const float*)d_in[7];
    const float* D_param   = (const float*)d_in[8];
    const float* out_proj_w= (const float*)d_in[9];
    const float* norm_w    = (const float*)d_in[10];
    const float* out_fc_w  = (const float*)d_in[11];
    const float* out_fc_b  = (const float*)d_in[12];
    const float* mu_w      = (const float*)d_in[13];
    const float* mu_b      = (const float*)d_in[14];
    const float* sigma_w   = (const float*)d_in[15];
    const float* sigma_b   = (const float*)d_in[16];
    float* ws = (float*)d_ws;
    float* out = (float*)d_out;

    // zero xbar accumulator (atomicAdd target)
    hipMemsetAsync(ws + OFF_XBAR, 0, BATCH * D_MODEL * sizeof(float), stream);

    k1_rmsnorm_inproj<<<NPOS / TP1, 256, 0, stream>>>(
        x, in_proj_w, norm_w, ws + OFF_XS, ws + OFF_Z, ws + OFF_XBAR);

    k2f_conv_scan<<<BATCH * NC2, 192, 0, stream>>>(
        ws + OFF_XS, ws + OFF_Z, conv_w, conv_b, x_proj_w,
        dt_proj_w, dt_proj_b, A_log, D_param,
        (float4*)(ws + OFF_OUT4));

    k4_head<<<BATCH, 192, 0, stream>>>(
        (const float4*)(ws + OFF_OUT4), ws + OFF_XBAR, out_proj_w,
        out_fc_w, out_fc_b, mu_w, mu_b, sigma_w, sigma_b, out);
}

// Round 6
// 267.374 us; speedup vs baseline: 3.7700x; 1.1678x over previous
//
#include <hip/hip_runtime.h>
#include <math.h>

#define BATCH 16
#define SEQLEN 4096
#define D_MODEL 96
#define D_STATE 6
#define D_CONV 9
#define D_INNER 192
#define DT_RANK 6
#define NPOS (BATCH * SEQLEN)

#define NC2 128            // chunks per sequence
#define CT2 (SEQLEN / NC2) // 32 steps per chunk

// workspace layout (in floats)
#define OFF_XS    0L
#define OFF_Z     (OFF_XS   + (long)NPOS * D_INNER)
#define OFF_OUT4  (OFF_Z    + (long)NPOS * D_INNER)   // float4 planes: B*NC2*5*192 float4s
#define OFF_XBAR  (OFF_OUT4 + (long)BATCH * NC2 * 5 * 192 * 4)

typedef short v8s __attribute__((ext_vector_type(8)));   // 8 x bf16 (MFMA A/B frag)
typedef float v4f __attribute__((ext_vector_type(4)));   // MFMA C/D frag

// fast transcendentals — abs threshold 2e-2, ample headroom
__device__ __forceinline__ float silu_fast(float v) {
    return __fdividef(v, 1.0f + __expf(-v));
}
__device__ __forceinline__ float softplus_fast(float v) {
    return (v > 20.0f) ? v : __logf(1.0f + __expf(v));
}
__device__ __forceinline__ float eluf(float v) {
    return (v > 0.0f) ? v : expm1f(v);
}
// pack two fp32 -> bf16x2 (RNE)
__device__ __forceinline__ unsigned int pack_bf16(float a, float b) {
    unsigned int ua = __float_as_uint(a), ub = __float_as_uint(b);
    ua += 0x7FFFu + ((ua >> 16) & 1u);
    ub += 0x7FFFu + ((ub >> 16) & 1u);
    return (ua >> 16) | (ub & 0xFFFF0000u);
}

// ---------------------------------------------------------------------------
// K1 (MFMA): RMSNorm (fp32) + in_proj via bf16 mfma_f32_16x16x32.
// Block: 256 threads (4 waves), 64 positions. Wave w owns output cols
// [w*96, w*96+96) -> waves 0,1 write xs, waves 2,3 write z (wave-uniform).
// LDS overlay: hRow(fp32 raw x, stride 101) shares space with WB (bf16 W
// K-chunk, [j][k] stride 20 dw); hA = bf16 h [pos][k] stride 52 dw.
// A-frag: lane holds h[m=lane&15][k=quad*8+j]; B-frag: W[n=lane&15][k=...]
// (identical map — W is [j][d] row-major = B^T). C/D: col=lane&15,
// row=quad*4+reg (verified layout, learn_hip m89/m91).
// ---------------------------------------------------------------------------
#define TP1 64
__global__ __launch_bounds__(256, 3) void k1_rmsnorm_inproj(
    const float* __restrict__ x, const float* __restrict__ W,
    const float* __restrict__ norm_w,
    float* __restrict__ xs, float* __restrict__ z, float* __restrict__ xbar)
{
    __shared__ unsigned int s_ovl[7680];   // 30.7 KB: hRow (6464 f) / WB (7680 dw)
    __shared__ unsigned int s_hA[64 * 52]; // 13.3 KB bf16 pairs [pos][dpair]
    __shared__ float s_scale[TP1];
    float* hRow = (float*)s_ovl;           // [p][d], stride 101
    unsigned int* WB = s_ovl;              // [j][kpair], stride 20 dw

    const int tid = threadIdx.x;
    const long p0 = (long)blockIdx.x * TP1;
    const int b = (int)(p0 / SEQLEN);

    // 1) stage raw x -> hRow (coalesced)
    for (int i = tid; i < TP1 * 96; i += 256) {
        int p = i / 96, d = i - p * 96;
        hRow[p * 101 + d] = x[p0 * 96 + i];
    }
    __syncthreads();

    // 2) per-pos rms scale (stride 101 -> conflict-free); xbar row-sums
    if (tid < TP1) {
        float ss = 0.0f;
        for (int d = 0; d < 96; d++) { float v = hRow[tid * 101 + d]; ss += v * v; }
        s_scale[tid] = 1.0f / sqrtf(ss / 96.0f + 1e-5f);
    } else if (tid < TP1 + 96) {
        int d = tid - TP1;
        float s = 0.0f;
        for (int p = 0; p < TP1; p++) s += hRow[p * 101 + d];
        atomicAdd(&xbar[b * 96 + d], s);   // xbar sums RAW x
    }
    __syncthreads();

    // 3) normalize + convert -> hA bf16 [pos][k] (3072 dword-pairs, 12 iters)
    {
        const float2* nw2 = (const float2*)norm_w;
        for (int i = tid; i < TP1 * 48; i += 256) {
            int p = i / 48, dp = i - p * 48;
            float sc = s_scale[p];
            float2 nv = nw2[dp];
            float v0 = hRow[p * 101 + 2 * dp]     * sc * nv.x;
            float v1 = hRow[p * 101 + 2 * dp + 1] * sc * nv.y;
            s_hA[p * 52 + dp] = pack_bf16(v0, v1);
        }
    }

    const int wave = tid >> 6, lane = tid & 63;
    const int quad = lane >> 4, ln = lane & 15;
    const int n0 = wave * 96;

    v4f acc[4][6];
#pragma unroll
    for (int mt = 0; mt < 4; mt++)
#pragma unroll
        for (int nt = 0; nt < 6; nt++) acc[mt][nt] = (v4f){0.f, 0.f, 0.f, 0.f};

    for (int kc = 0; kc < 3; kc++) {
        __syncthreads();   // WB readers done (kc=0: hRow readers done)
        // stage W[:, kc*32 .. +32) as bf16 into WB
        for (int i = tid; i < 384 * 16; i += 256) {
            int j = i >> 4, kp = i & 15;
            const float2 wv = *(const float2*)&W[j * 96 + kc * 32 + 2 * kp];
            WB[j * 20 + kp] = pack_bf16(wv.x, wv.y);
        }
        __syncthreads();

        v8s af[4];
#pragma unroll
        for (int mt = 0; mt < 4; mt++)
            af[mt] = *(const v8s*)&s_hA[(mt * 16 + ln) * 52 + kc * 16 + quad * 4];
#pragma unroll
        for (int nt = 0; nt < 6; nt++) {
            v8s bf = *(const v8s*)&WB[(n0 + nt * 16 + ln) * 20 + quad * 4];
#pragma unroll
            for (int mt = 0; mt < 4; mt++)
                acc[mt][nt] = __builtin_amdgcn_mfma_f32_16x16x32_bf16(
                    af[mt], bf, acc[mt][nt], 0, 0, 0);
        }
    }

    // epilogue: C/D layout col=ln, row=quad*4+r
    float* dst = (wave < 2) ? xs : z;
    const int jbase = (wave & 1) * 96 + ln;
#pragma unroll
    for (int mt = 0; mt < 4; mt++) {
#pragma unroll
        for (int r = 0; r < 4; r++) {
            long pos = p0 + mt * 16 + quad * 4 + r;
            float* drow = &dst[pos * D_INNER + jbase];
#pragma unroll
            for (int nt = 0; nt < 6; nt++) drow[nt * 16] = acc[mt][nt][r];
        }
    }
}

// ---------------------------------------------------------------------------
// K2F: fused conv+silu -> xc (LDS); dbc GEMM -> delta_r/Bm/Cm (packed LDS);
// chunk-local scan pass A with G-trick. z prefetched into 32 registers.
// ---------------------------------------------------------------------------
#define XSTR2 196
__global__ __launch_bounds__(192, 3) void k2f_conv_scan(
    const float* __restrict__ xs, const float* __restrict__ z,
    const float* __restrict__ conv_w, const float* __restrict__ conv_b,
    const float* __restrict__ x_proj_w,
    const float* __restrict__ dt_w, const float* __restrict__ dt_b,
    const float* __restrict__ A_log, const float* __restrict__ D_param,
    float4* __restrict__ out4)
{
    __shared__ float sxc[CT2 * XSTR2];   // 25.1 KB xc tile [t][e]
    __shared__ float sxp[18 * XSTR2];    // 14.1 KB x_proj_w
    __shared__ float sMeta[CT2][20];     // 2.5 KB: [0:6) dr, [8:14) Bm, [14:20) Cm
    const int e = threadIdx.x;
    const int c = blockIdx.x & (NC2 - 1);
    const int b = blockIdx.x >> 7;
    const int l0 = c * CT2;
    const long brow = (long)b * SEQLEN;

    for (int i = e; i < 18 * 192; i += 192) {
        int f = i / 192, kk = i - f * 192;
        sxp[f * XSTR2 + kk] = x_proj_w[i];
    }

    float cw[D_CONV];
#pragma unroll
    for (int k = 0; k < D_CONV; k++) cw[k] = conv_w[e * D_CONV + k];
    const float cb = conv_b[e];
    float win[D_CONV];
#pragma unroll
    for (int k = 0; k < 8; k++) {
        int ll = l0 - 8 + k;
        win[k] = (ll >= 0) ? xs[(brow + ll) * D_INNER + e] : 0.0f;
    }
    for (int r = 0; r < CT2; r++) {
        win[8] = xs[(brow + l0 + r) * D_INNER + e];
        float s = cb;
#pragma unroll
        for (int k = 0; k < D_CONV; k++) s += win[k] * cw[k];
        sxc[r * XSTR2 + e] = silu_fast(s);
#pragma unroll
        for (int k = 0; k < 8; k++) win[k] = win[k + 1];
    }

    // prefetch z for the whole chunk (independent loads in flight)
    const float* zp = &z[(brow + l0) * D_INNER + e];
    float zv[CT2];
#pragma unroll
    for (int t = 0; t < CT2; t++) zv[t] = zp[(long)t * D_INNER];
    __syncthreads();

    // dbc GEMM: thread -> (p = e/6 in [0,32), fg = e%6); f = fg, fg+6, fg+12
    {
        const int p = e / 6, fg = e - p * 6;
        const float4* xr = (const float4*)&sxc[p * XSTR2];
        const float4* w0 = (const float4*)&sxp[fg * XSTR2];
        const float4* w1 = (const float4*)&sxp[(fg + 6) * XSTR2];
        const float4* w2 = (const float4*)&sxp[(fg + 12) * XSTR2];
        float s0 = 0.0f, s1 = 0.0f, s2 = 0.0f;
#pragma unroll 4
        for (int kk = 0; kk < D_INNER / 4; kk++) {
            float4 xv = xr[kk];
            float4 a = w0[kk], bq = w1[kk], cc = w2[kk];
            s0 += xv.x * a.x + xv.y * a.y + xv.z * a.z + xv.w * a.w;
            s1 += xv.x * bq.x + xv.y * bq.y + xv.z * bq.z + xv.w * bq.w;
            s2 += xv.x * cc.x + xv.y * cc.y + xv.z * cc.z + xv.w * cc.w;
        }
        sMeta[p][fg] = s0;
        sMeta[p][8 + fg] = s1;
        sMeta[p][14 + fg] = s2;
    }
    __syncthreads();

    float a[D_STATE];
#pragma unroll
    for (int n = 0; n < D_STATE; n++) a[n] = -__expf(A_log[e * D_STATE + n]);
    float dtw[DT_RANK];
#pragma unroll
    for (int q = 0; q < DT_RANK; q++) dtw[q] = dt_w[e * DT_RANK + q];
    const float dtb = dt_b[e];
    const float Dv = D_param[e];

    float S[D_STATE], P[D_STATE], G[D_STATE];
#pragma unroll
    for (int n = 0; n < D_STATE; n++) { S[n] = 0.0f; P[n] = 1.0f; G[n] = 0.0f; }
    float ysum0 = 0.0f;

#pragma unroll 2
    for (int t = 0; t < CT2; t++) {
        const float4* m4 = (const float4*)&sMeta[t][0];
        float4 m0 = m4[0];
        float4 m1 = m4[1];
        float4 mB0 = m4[2];
        float4 mB1 = m4[3];
        float4 mC  = m4[4];
        float Bv[6] = {mB0.x, mB0.y, mB0.z, mB0.w, mB1.x, mB1.y};
        float Cv[6] = {mB1.z, mB1.w, mC.x, mC.y, mC.z, mC.w};
        float dr = dtb + m0.x * dtw[0] + m0.y * dtw[1] + m0.z * dtw[2]
                 + m0.w * dtw[3] + m1.x * dtw[4] + m1.y * dtw[5];
        float dl = softplus_fast(dr);
        float xv = sxc[t * XSTR2 + e];
        float zw = silu_fast(zv[t]);
        float dx = dl * xv;
        float y = Dv * xv;
#pragma unroll
        for (int n = 0; n < D_STATE; n++) {
            float dA = __expf(dl * a[n]);
            S[n] = dA * S[n] + dx * Bv[n];
            P[n] *= dA;
            y += S[n] * Cv[n];
            G[n] += zw * P[n] * Cv[n];
        }
        ysum0 += zw * y;
    }

    long ob = (long)(b * NC2 + c) * 5 * 192 + e;
    float4 q0, q1, q2, q3, q4;
    q0.x=P[0]; q0.y=P[1]; q0.z=P[2]; q0.w=P[3];
    q1.x=P[4]; q1.y=P[5]; q1.z=S[0]; q1.w=S[1];
    q2.x=S[2]; q2.y=S[3]; q2.z=S[4]; q2.w=S[5];
    q3.x=G[0]; q3.y=G[1]; q3.z=G[2]; q3.w=G[3];
    q4.x=G[4]; q4.y=G[5]; q4.z=ysum0; q4.w=0.0f;
    out4[ob          ] = q0;
    out4[ob + 192    ] = q1;
    out4[ob + 2 * 192] = q2;
    out4[ob + 3 * 192] = q3;
    out4[ob + 4 * 192] = q4;
}

// ---------------------------------------------------------------------------
// K4H: per-batch block: fold 128 chunks (carry-in) -> ybar; then output head.
// ---------------------------------------------------------------------------
__global__ __launch_bounds__(192) void k4_head(
    const float4* __restrict__ out4, const float* __restrict__ xbar,
    const float* __restrict__ Wout,
    const float* __restrict__ fc_w, const float* __restrict__ fc_b,
    const float* __restrict__ mu_w, const float* __restrict__ mu_b,
    const float* __restrict__ sg_w, const float* __restrict__ sg_b,
    float* __restrict__ out)
{
    __shared__ float ybar[D_INNER];
    __shared__ float evec[D_MODEL];
    __shared__ float feat_s[64];
    const int e = threadIdx.x;
    const int b = blockIdx.x;

    float H[D_STATE];
#pragma unroll
    for (int n = 0; n < D_STATE; n++) H[n] = 0.0f;
    float yb = 0.0f;
#pragma unroll 4
    for (int c = 0; c < NC2; c++) {
        long ob = (long)(b * NC2 + c) * 5 * 192 + e;
        float4 q0 = out4[ob];
        float4 q1 = out4[ob + 192];
        float4 q2 = out4[ob + 2 * 192];
        float4 q3 = out4[ob + 3 * 192];
        float4 q4 = out4[ob + 4 * 192];
        float Pv[6] = {q0.x, q0.y, q0.z, q0.w, q1.x, q1.y};
        float Sv[6] = {q1.z, q1.w, q2.x, q2.y, q2.z, q2.w};
        float Gv[6] = {q3.x, q3.y, q3.z, q3.w, q4.x, q4.y};
        float g = 0.0f;
#pragma unroll
        for (int n = 0; n < D_STATE; n++) g += Gv[n] * H[n];
        yb += q4.z + g;
#pragma unroll
        for (int n = 0; n < D_STATE; n++) H[n] = Pv[n] * H[n] + Sv[n];
    }
    ybar[e] = yb;
    __syncthreads();

    if (e < D_MODEL) {
        float s = xbar[b * D_MODEL + e];
        const float* wrow = &Wout[e * D_INNER];
        for (int e2 = 0; e2 < D_INNER; e2++) s += ybar[e2] * wrow[e2];
        evec[e] = s / (float)SEQLEN;
    }
    __syncthreads();

    if (e < 64) {
        float s = fc_b[e];
        const float* wrow = &fc_w[e * D_MODEL];
        for (int d = 0; d < D_MODEL; d++) s += evec[d] * wrow[d];
        float f = eluf(tanhf(s));
        feat_s[e] = f;
        out[b * 64 + e] = f; // feat
    }
    __syncthreads();

    if (e < 64) {
        float smu = mu_b[e], ssg = sg_b[e];
        const float* mrow = &mu_w[e * 64];
        const float* srow = &sg_w[e * 64];
        for (int i = 0; i < 64; i++) {
            smu += feat_s[i] * mrow[i];
            ssg += feat_s[i] * srow[i];
        }
        out[1024 + b * 64 + e] = smu;                        // mu
        out[2048 + b * 64 + e] = eluf(ssg) + 1.0f + 1e-14f;  // sigma
    }
}

extern "C" void kernel_launch(void* const* d_in, const int* in_sizes, int n_in,
                              void* d_out, int out_size, void* d_ws, size_t ws_size,
                              hipStream_t stream) {
    const float* x         = (const float*)d_in[0];
    const float* in_proj_w = (const float*)d_in[1];
    const float* conv_w    = (const float*)d_in[2];
    const float* conv_b    = (const float*)d_in[3];
    const float* x_proj_w  = (const float*)d_in[4];
    const float* dt_proj_w = (const float*)d_in[5];
    const float* dt_proj_b = (const float*)d_in[6];
    const float* A_log     = (const float*)d_in[7];
    const float* D_param   = (const float*)d_in[8];
    const float* out_proj_w= (const float*)d_in[9];
    const float* norm_w    = (const float*)d_in[10];
    const float* out_fc_w  = (const float*)d_in[11];
    const float* out_fc_b  = (const float*)d_in[12];
    const float* mu_w      = (const float*)d_in[13];
    const float* mu_b      = (const float*)d_in[14];
    const float* sigma_w   = (const float*)d_in[15];
    const float* sigma_b   = (const float*)d_in[16];
    float* ws = (float*)d_ws;
    float* out = (float*)d_out;

    // zero xbar accumulator (atomicAdd target)
    hipMemsetAsync(ws + OFF_XBAR, 0, BATCH * D_MODEL * sizeof(float), stream);

    k1_rmsnorm_inproj<<<NPOS / TP1, 256, 0, stream>>>(
        x, in_proj_w, norm_w, ws + OFF_XS, ws + OFF_Z, ws + OFF_XBAR);

    k2f_conv_scan<<<BATCH * NC2, 192, 0, stream>>>(
        ws + OFF_XS, ws + OFF_Z, conv_w, conv_b, x_proj_w,
        dt_proj_w, dt_proj_b, A_log, D_param,
        (float4*)(ws + OFF_OUT4));

    k4_head<<<BATCH, 192, 0, stream>>>(
        (const float4*)(ws + OFF_OUT4), ws + OFF_XBAR, out_proj_w,
        out_fc_w, out_fc_b, mu_w, mu_b, sigma_w, sigma_b, out);
}